// Round 11
// baseline (144.327 us; speedup 1.0000x reference)
//
#include <hip/hip_runtime.h>
#include <math.h>

#define B 4
#define P 32768
#define C 8
#define F 32
#define D 64
#define H 64

typedef __attribute__((ext_vector_type(8))) short bf16x8;
typedef __attribute__((ext_vector_type(4))) float f32x4;

__device__ __forceinline__ short f2bf(float f) {
    union { float f; unsigned u; } v; v.f = f;
    unsigned r = (v.u + 0x7FFFu + ((v.u >> 16) & 1u)) >> 16;   // RNE
    return (short)r;
}

// packed f32x2 -> bf16x2 (RNE) in one VALU op
__device__ __forceinline__ unsigned cvt_pk_bf16(float lo, float hi) {
    unsigned r;
    asm("v_cvt_pk_bf16_f32 %0, %1, %2" : "=v"(r) : "v"(lo), "v"(hi));
    return r;
}

// async global->LDS, 16B per lane. LDS dest = wave-uniform base + lane*16;
// global src = per-lane address (guide §5).
__device__ __forceinline__ void gload_lds16(const void* g, void* s) {
    __builtin_amdgcn_global_load_lds(
        (const __attribute__((address_space(1))) unsigned*)g,
        (__attribute__((address_space(3))) unsigned*)s, 16, 0, 0);
}

// ---------------------------------------------------------------------------
// repack_relu (r7, verified): D-form accumulators -> B-frag pair IN-LANE.
// pi(32f+8q+j) = 16(2f+(j>>2)) + 4q + (j&3) permutes the k-axis so lane
// (q,l16)'s D-form values {n=16nt+4q+r} ARE its B-frags in register order.
// Weights absorb pi at setup. Cost: 16 fmax + 8 cvt_pk. No shuffles, no LDS.
// ---------------------------------------------------------------------------
__device__ __forceinline__ void repack_relu(const f32x4* v, bf16x8& f0, bf16x8& f1)
{
    union { unsigned u[4]; bf16x8 v8; } A, Bv;
    A.u[0]  = cvt_pk_bf16(fmaxf(v[0][0], 0.f), fmaxf(v[0][1], 0.f));
    A.u[1]  = cvt_pk_bf16(fmaxf(v[0][2], 0.f), fmaxf(v[0][3], 0.f));
    A.u[2]  = cvt_pk_bf16(fmaxf(v[1][0], 0.f), fmaxf(v[1][1], 0.f));
    A.u[3]  = cvt_pk_bf16(fmaxf(v[1][2], 0.f), fmaxf(v[1][3], 0.f));
    Bv.u[0] = cvt_pk_bf16(fmaxf(v[2][0], 0.f), fmaxf(v[2][1], 0.f));
    Bv.u[1] = cvt_pk_bf16(fmaxf(v[2][2], 0.f), fmaxf(v[2][3], 0.f));
    Bv.u[2] = cvt_pk_bf16(fmaxf(v[3][0], 0.f), fmaxf(v[3][1], 0.f));
    Bv.u[3] = cvt_pk_bf16(fmaxf(v[3][2], 0.f), fmaxf(v[3][3], 0.f));
    f0 = A.v8; f1 = Bv.v8;
}

// ---------------------------------------------------------------------------
// Merged setup kernel (EXACTLY r7/r10 — verified). Bxt natural n rows with
// XOR swizzle short_idx ^= (row&7)<<3 (conflict-free staged ds_read_b128,
// rule #21: baked into global source; gload_lds is linear).
// Wa/Wb pi-permuted (storage[n_out][kslot] = W[pi(kslot)][n_out]).
// ---------------------------------------------------------------------------
__global__ __launch_bounds__(256)
void setup_kernel(const float* __restrict__ z,
                  const float* __restrict__ W_dir,
                  const float* __restrict__ W0,
                  const float* __restrict__ b0,
                  const float* __restrict__ Wa,
                  const float* __restrict__ Wb,
                  short* __restrict__ Bxt,
                  short* __restrict__ Wat,
                  short* __restrict__ Wbt)
{
    if (blockIdx.x >= 32) {
        int idx = (blockIdx.x - 32) * 256 + threadIdx.x;  // < 5*64*64
        int i = idx >> 12, r = idx & 4095, ks = r >> 6, n = r & 63;
        int f = ks >> 5, q = (ks >> 3) & 3, j = ks & 7;
        int nin = 16 * (2 * f + (j >> 2)) + 4 * q + (j & 3);   // pi(kslot)
        int o   = (i << 12) + (n << 6) + ks;                   // [n_out][kslot]
        int src = (i << 12) + (nin << 6) + n;                  // W[i][nin][n]
        Wat[o] = f2bf(Wa[src]);
        Wbt[o] = f2bf(Wb[src]);
        return;
    }
    const int bc = blockIdx.x;
    const int t  = threadIdx.x & 63;     // output column n (natural row)
    const int g  = threadIdx.x >> 6;     // f-group 0..3
    const float* zb = z + (size_t)bc * F * D;

    __shared__ float zl[F][D];       // 8 KB
    __shared__ float wdir[D][D];     // 16 KB
    __shared__ float w0m[D][H];      // 16 KB (W0 rows 1..64)
    __shared__ float zp[4][D];       // 1 KB
    __shared__ float zq[4][D];       // 1 KB

    for (int i = threadIdx.x; i < F * D; i += 256) zl[i >> 6][i & 63] = zb[i];
    for (int i = threadIdx.x; i < D * D; i += 256) wdir[i >> 6][i & 63] = W_dir[i];
    for (int i = threadIdx.x; i < D * H; i += 256) w0m[i >> 6][i & 63] = W0[H + i];
    __syncthreads();

    const int sw = (t & 7) << 3;                      // bank swizzle (shorts)
    short* brow = Bxt + ((size_t)bc * 64 + t) * 64;   // natural row = n

    float zi = 0.f;
    for (int f = g * 8; f < g * 8 + 8; ++f) {
        float z0 = 0, z1 = 0, z2 = 0, z3 = 0;
        float a0 = 0, a1 = 0, a2 = 0, a3 = 0;
#pragma unroll
        for (int d = 0; d < D; d += 4) {
            float4 z4 = *(const float4*)&zl[f][d];    // broadcast b128
            z0 += z4.x * wdir[d + 0][t];
            z1 += z4.y * wdir[d + 1][t];
            z2 += z4.z * wdir[d + 2][t];
            z3 += z4.w * wdir[d + 3][t];
            a0 += z4.x * w0m[d + 0][t];
            a1 += z4.y * w0m[d + 1][t];
            a2 += z4.z * w0m[d + 2][t];
            a3 += z4.w * w0m[d + 3][t];
        }
        zi += zl[f][t] * ((z0 + z1) + (z2 + z3));
        brow[f ^ sw] = f2bf((a0 + a1) + (a2 + a3));   // ZW row f, col t
    }
    zp[g][t] = zi;
    __syncthreads();
    if (g == 0) {
        float zall = zp[0][t] + zp[1][t] + zp[2][t] + zp[3][t];
        zp[0][t] = zall;                              // full z_inv[t]
    }
    __syncthreads();
    // zc partials: each g-group covers 16 e's
    {
        float zcp = 0.f;
        for (int e = g * 16; e < g * 16 + 16; ++e)
            zcp += zp[0][e] * W0[(65 + e) * H + t];
        zq[g][t] = zcp;
    }
    __syncthreads();
    if (g == 0) {
        brow[32 ^ sw] = f2bf(W0[t]);                  // multiplies s2
        float zc = b0[t] + zq[0][t] + zq[1][t] + zq[2][t] + zq[3][t];
        brow[33 ^ sw] = f2bf(zc);                     // multiplies 1
    } else if (g == 1) {
        for (int k = 34; k < 64; ++k) brow[k ^ sw] = 0;
    }
}

// ---------------------------------------------------------------------------
// Main. r11: r10 champion (63.9 µs) with VALU THINNING + setprio:
// (1) biases/zero passed DIRECTLY as the first MFMA's C operand (f32x4
//     quads; D!=C is legal) — removes ~512 per-wave acc-init v_movs.
// (2) S1 LDS addressing hoisted: sw=(l16&7)<<3 is nt-independent, so the two
//     per-lane byte offsets are loop-invariant; nt becomes an imm offset.
// (3) s_setprio(1) around the pure-MFMA S2/S3/residual clusters (T5: our
//     waves are barrier-free most of the iter -> role diversity, attn-like).
// Barrier schedule, 4-slot staging, repack, swizzle: unchanged from r10.
// Gates: VGPR <= 128 and WRITE_SIZE ~512 KB (any spill -> revert).
// launch_bounds(256,2): the 128-reg / 4-waves-per-SIMD bucket (r9: crossing
// 128 halves occupancy; <=64 unreachable for this algorithm's state).
// ---------------------------------------------------------------------------
__global__ __launch_bounds__(256, 2)
void main_kernel(const float* __restrict__ p,      // (B,P,3)
                 const float* __restrict__ pos,    // (B,3)
                 const float* __restrict__ W_feat, // (3,F)
                 const short* __restrict__ Bxt,    // (B,C,64n,64k) bf16 (swz)
                 const short* __restrict__ Wat,    // (5,64n,64kslot) pi-perm
                 const short* __restrict__ Wbt,    // (5,64n,64kslot) pi-perm
                 const float* __restrict__ ba,     // (5,H)
                 const float* __restrict__ bb,     // (5,H)
                 const float* __restrict__ Wout,   // (H,1)
                 const float* __restrict__ bout,   // (1,)
                 float* __restrict__ out)          // (B,P)
{
    const int wave = threadIdx.x >> 6;
    const int lane = threadIdx.x & 63;
    const int quad = lane >> 4;
    const int l16  = lane & 15;
    const int b    = blockIdx.y;
    const int base = blockIdx.x * 128 + wave * 32;

    __shared__ __attribute__((aligned(16))) short bxlds[4][4096]; // 32 KB

    const short* bxg = Bxt + (size_t)b * C * 4096;

    // ---- stage channels 0-3 (2 gloads per wave per channel)
#pragma unroll
    for (int c0 = 0; c0 < 4; ++c0) {
        const short* src = bxg + (size_t)c0 * 4096 + (wave * 2) * 512 + lane * 8;
        gload_lds16(src,       &bxlds[c0][(wave * 2) * 512]);
        gload_lds16(src + 512, &bxlds[c0][(wave * 2 + 1) * 512]);
    }

    // ---- point features -> B-frags for both m-tiles
    bf16x8 a0[2], a1[2];
#pragma unroll
    for (int m = 0; m < 2; ++m) {
        const float* pp = p + ((size_t)b * P + base + m * 16 + l16) * 3;
        float px = pp[0] - pos[b * 3 + 0];
        float py = pp[1] - pos[b * 3 + 1];
        float pz = pp[2] - pos[b * 3 + 2];
        float nrm = sqrtf(px * px + py * py + pz * pz);
        if (nrm > 0.5f) { float s = 0.5f / nrm; px *= s; py *= s; pz *= s; }
        float av[8];
        float s2 = 0.f;
#pragma unroll
        for (int j = 0; j < 8; ++j) {
            int k = quad * 8 + j;
            av[j] = px * W_feat[k] + py * W_feat[F + k] + pz * W_feat[2 * F + k];
            s2 += av[j] * av[j];
        }
        s2 += __shfl_xor(s2, 16);
        s2 += __shfl_xor(s2, 32);
        union { bf16x8 v; unsigned u[4]; } ua;
#pragma unroll
        for (int j = 0; j < 4; ++j) ua.u[j] = cvt_pk_bf16(av[2 * j], av[2 * j + 1]);
        a0[m] = ua.v;
        union { bf16x8 v; unsigned u[4]; } ub;
#pragma unroll
        for (int j = 0; j < 4; ++j) ub.u[j] = 0;
        if (quad == 0) ub.u[0] = cvt_pk_bf16(s2, 1.0f);
        a1[m] = ub.v;
    }

    f32x4 pooled[2][4];
#pragma unroll
    for (int m = 0; m < 2; ++m)
#pragma unroll
        for (int nt = 0; nt < 4; ++nt)
            pooled[m][nt] = (f32x4){-1e30f, -1e30f, -1e30f, -1e30f};

    // ---- biases as f32x4 quads (direct C-operand; no reconstruction movs)
    f32x4 ba0q[4], bb0q[4];
#pragma unroll
    for (int nt = 0; nt < 4; ++nt) {
        ba0q[nt] = *(const f32x4*)(ba + nt * 16 + 4 * quad);
        bb0q[nt] = *(const f32x4*)(bb + nt * 16 + 4 * quad);
    }
    const f32x4 zeroq = (f32x4){0.f, 0.f, 0.f, 0.f};

    // ---- hoist layer-0 weight A-frags (c-invariant; 64 VGPRs)
    bf16x8 wa0f[4][2], wb0f[4][2];
#pragma unroll
    for (int nt = 0; nt < 4; ++nt) {
        wa0f[nt][0] = *(const bf16x8*)(Wat + (nt * 16 + l16) * 64 + quad * 8);
        wa0f[nt][1] = *(const bf16x8*)(Wat + (nt * 16 + l16) * 64 + 32 + quad * 8);
        wb0f[nt][0] = *(const bf16x8*)(Wbt + (nt * 16 + l16) * 64 + quad * 8);
        wb0f[nt][1] = *(const bf16x8*)(Wbt + (nt * 16 + l16) * 64 + 32 + quad * 8);
    }

    // ---- loop-invariant S1 LDS offsets (shorts): sw is nt-independent
    const int swl = (l16 & 7) << 3;
    const int o0 = l16 * 64 + ((quad * 8) ^ swl);
    const int o1 = l16 * 64 + ((32 + quad * 8) ^ swl);

    __syncthreads();   // drains vmcnt: bxlds[0..3] published

    // =============== c-loop: 4 barriers total =============================
#pragma unroll 1
    for (int c = 0; c < C; ++c) {
        const short* bxs = &bxlds[c & 3][0];

        // ---- S1: x[n, point] = mfma(A=Bxt rows, B=point-feat frag)
        f32x4 x[2][4];
#pragma unroll
        for (int nt = 0; nt < 4; ++nt) {
            bf16x8 b0f = *(const bf16x8*)(bxs + nt * 1024 + o0);
            bf16x8 b1f = *(const bf16x8*)(bxs + nt * 1024 + o1);
#pragma unroll
            for (int m = 0; m < 2; ++m) {
                f32x4 acc = __builtin_amdgcn_mfma_f32_16x16x32_bf16(b0f, a0[m], zeroq, 0, 0, 0);
                acc = __builtin_amdgcn_mfma_f32_16x16x32_bf16(b1f, a1[m], acc, 0, 0, 0);
                x[m][nt] = acc;
            }
        }

        // ---- repack relu(x) -> B-frags (in-lane, zero shuffles)
        bf16x8 xf0[2], xf1[2];
#pragma unroll
        for (int m = 0; m < 2; ++m) repack_relu(x[m], xf0[m], xf1[m]);

        // ---- S2: h = relu(x) @ Wa0 + ba0 (bias as C of first MFMA)
        f32x4 h[2][4];
        __builtin_amdgcn_s_setprio(1);
#pragma unroll
        for (int nt = 0; nt < 4; ++nt) {
#pragma unroll
            for (int m = 0; m < 2; ++m) {
                f32x4 acc = __builtin_amdgcn_mfma_f32_16x16x32_bf16(wa0f[nt][0], xf0[m], ba0q[nt], 0, 0, 0);
                acc = __builtin_amdgcn_mfma_f32_16x16x32_bf16(wa0f[nt][1], xf1[m], acc, 0, 0, 0);
                h[m][nt] = acc;
            }
        }
        __builtin_amdgcn_s_setprio(0);

        // ---- repack relu(h)
        bf16x8 hf0[2], hf1[2];
#pragma unroll
        for (int m = 0; m < 2; ++m) repack_relu(h[m], hf0[m], hf1[m]);

        // ---- S3: x + relu(h) @ Wb0 ; max-pool over c (bb0 folded post-loop)
        __builtin_amdgcn_s_setprio(1);
#pragma unroll
        for (int nt = 0; nt < 4; ++nt) {
#pragma unroll
            for (int m = 0; m < 2; ++m) {
                f32x4 acc = __builtin_amdgcn_mfma_f32_16x16x32_bf16(wb0f[nt][0], hf0[m], x[m][nt], 0, 0, 0);
                acc = __builtin_amdgcn_mfma_f32_16x16x32_bf16(wb0f[nt][1], hf1[m], acc, 0, 0, 0);
#pragma unroll
                for (int r = 0; r < 4; ++r)
                    pooled[m][nt][r] = fmaxf(pooled[m][nt][r], acc[r]);
            }
        }
        __builtin_amdgcn_s_setprio(0);

        // ---- barrier schedule: WAR/drain points only (r10, verified)
        if (c == 1) {
            __syncthreads();   // all waves past reads of slots 0,1
#pragma unroll
            for (int cc = 4; cc < 6; ++cc) {
                const short* src = bxg + (size_t)cc * 4096 + (wave * 2) * 512 + lane * 8;
                gload_lds16(src,       &bxlds[cc & 3][(wave * 2) * 512]);
                gload_lds16(src + 512, &bxlds[cc & 3][(wave * 2 + 1) * 512]);
            }
        } else if (c == 3) {
            __syncthreads();   // drains ch4/5 gloads; all past reads of s2,s3
#pragma unroll
            for (int cc = 6; cc < 8; ++cc) {
                const short* src = bxg + (size_t)cc * 4096 + (wave * 2) * 512 + lane * 8;
                gload_lds16(src,       &bxlds[cc & 3][(wave * 2) * 512]);
                gload_lds16(src + 512, &bxlds[cc & 3][(wave * 2 + 1) * 512]);
            }
        } else if (c == 5) {
            __syncthreads();   // drains ch6/7 gloads before c=6 reads
        }
    }

    // ---- fold bb0 into pooled once (moved out of the c-loop)
#pragma unroll
    for (int nt = 0; nt < 4; ++nt)
#pragma unroll
        for (int m = 0; m < 2; ++m)
#pragma unroll
            for (int r = 0; r < 4; ++r)
                pooled[m][nt][r] += bb0q[nt][r];

    // =============== residual blocks 1..4 (2 chains: m-tiles) ===============
#pragma unroll
    for (int i = 1; i < 5; ++i) {
        const short* wa = Wat + i * 4096;
        const short* wb = Wbt + i * 4096;
        f32x4 baiq[4], bbiq[4];
#pragma unroll
        for (int nt = 0; nt < 4; ++nt) {
            baiq[nt] = *(const f32x4*)(ba + i * H + nt * 16 + 4 * quad);
            bbiq[nt] = *(const f32x4*)(bb + i * H + nt * 16 + 4 * quad);
        }

        bf16x8 pf0[2], pf1[2];
#pragma unroll
        for (int m = 0; m < 2; ++m) repack_relu(pooled[m], pf0[m], pf1[m]);

        f32x4 h[2][4];
        __builtin_amdgcn_s_setprio(1);
#pragma unroll
        for (int nt = 0; nt < 4; ++nt) {
            bf16x8 w0f = *(const bf16x8*)(wa + (nt * 16 + l16) * 64 + quad * 8);
            bf16x8 w1f = *(const bf16x8*)(wa + (nt * 16 + l16) * 64 + 32 + quad * 8);
#pragma unroll
            for (int m = 0; m < 2; ++m) {
                f32x4 acc = __builtin_amdgcn_mfma_f32_16x16x32_bf16(w0f, pf0[m], baiq[nt], 0, 0, 0);
                acc = __builtin_amdgcn_mfma_f32_16x16x32_bf16(w1f, pf1[m], acc, 0, 0, 0);
                h[m][nt] = acc;
            }
        }
        __builtin_amdgcn_s_setprio(0);

        bf16x8 hf0[2], hf1[2];
#pragma unroll
        for (int m = 0; m < 2; ++m) repack_relu(h[m], hf0[m], hf1[m]);

        __builtin_amdgcn_s_setprio(1);
#pragma unroll
        for (int nt = 0; nt < 4; ++nt) {
            bf16x8 w0f = *(const bf16x8*)(wb + (nt * 16 + l16) * 64 + quad * 8);
            bf16x8 w1f = *(const bf16x8*)(wb + (nt * 16 + l16) * 64 + 32 + quad * 8);
#pragma unroll
            for (int m = 0; m < 2; ++m) {
                f32x4 acc = pooled[m][nt];
#pragma unroll
                for (int r = 0; r < 4; ++r) acc[r] += bbiq[nt][r];
                acc = __builtin_amdgcn_mfma_f32_16x16x32_bf16(w0f, hf0[m], acc, 0, 0, 0);
                acc = __builtin_amdgcn_mfma_f32_16x16x32_bf16(w1f, hf1[m], acc, 0, 0, 0);
                pooled[m][nt] = acc;
            }
        }
        __builtin_amdgcn_s_setprio(0);
    }

    // =============== head: per-lane dot + cross-quad reduce =================
    const float bo = bout[0];
    f32x4 wo4[4];
#pragma unroll
    for (int nt = 0; nt < 4; ++nt)
        wo4[nt] = *(const f32x4*)(Wout + nt * 16 + 4 * quad);
#pragma unroll
    for (int m = 0; m < 2; ++m) {
        float s = 0.f;
#pragma unroll
        for (int nt = 0; nt < 4; ++nt)
#pragma unroll
            for (int r = 0; r < 4; ++r)
                s += fmaxf(pooled[m][nt][r], 0.f) * wo4[nt][r];
        s += __shfl_xor(s, 16);
        s += __shfl_xor(s, 32);
        if (lane < 16)
            out[(size_t)b * P + base + m * 16 + l16] = s + bo;
    }
}

extern "C" void kernel_launch(void* const* d_in, const int* in_sizes, int n_in,
                              void* d_out, int out_size, void* d_ws, size_t ws_size,
                              hipStream_t stream) {
    const float* z      = (const float*)d_in[0];
    const float* pos    = (const float*)d_in[1];
    const float* p      = (const float*)d_in[2];
    const float* W_feat = (const float*)d_in[3];
    const float* W_dir  = (const float*)d_in[4];
    const float* W0     = (const float*)d_in[5];
    const float* b0     = (const float*)d_in[6];
    const float* Wa     = (const float*)d_in[7];
    const float* ba     = (const float*)d_in[8];
    const float* Wb     = (const float*)d_in[9];
    const float* bb     = (const float*)d_in[10];
    const float* Wout   = (const float*)d_in[11];
    const float* bout   = (const float*)d_in[12];
    float* out = (float*)d_out;

    short* wsS = (short*)d_ws;
    short* Bxt = wsS;                    // B*C*64*64 shorts
    short* Wat = wsS + 32 * 4096;        // 5*4096
    short* Wbt = Wat + 5 * 4096;         // 5*4096

    setup_kernel<<<112, 256, 0, stream>>>(z, W_dir, W0, b0, Wa, Wb, Bxt, Wat, Wbt);

    dim3 grid(P / 128, B);
    main_kernel<<<grid, 256, 0, stream>>>(p, pos, W_feat, Bxt, Wat, Wbt,
                                          ba, bb, Wout, bout, out);
}

// Round 12
// 142.544 us; speedup vs baseline: 1.0125x; 1.0125x over previous
//
#include <hip/hip_runtime.h>
#include <math.h>

#define B 4
#define P 32768
#define C 8
#define F 32
#define D 64
#define H 64

typedef __attribute__((ext_vector_type(8))) short bf16x8;
typedef __attribute__((ext_vector_type(4))) float f32x4;

__device__ __forceinline__ short f2bf(float f) {
    union { float f; unsigned u; } v; v.f = f;
    unsigned r = (v.u + 0x7FFFu + ((v.u >> 16) & 1u)) >> 16;   // RNE
    return (short)r;
}

// packed f32x2 -> bf16x2 (RNE) in one VALU op
__device__ __forceinline__ unsigned cvt_pk_bf16(float lo, float hi) {
    unsigned r;
    asm("v_cvt_pk_bf16_f32 %0, %1, %2" : "=v"(r) : "v"(lo), "v"(hi));
    return r;
}

// async global->LDS, 16B per lane. LDS dest = wave-uniform base + lane*16;
// global src = per-lane address (guide §5).
__device__ __forceinline__ void gload_lds16(const void* g, void* s) {
    __builtin_amdgcn_global_load_lds(
        (const __attribute__((address_space(1))) unsigned*)g,
        (__attribute__((address_space(3))) unsigned*)s, 16, 0, 0);
}

// ---------------------------------------------------------------------------
// repack_relu (r7, verified): D-form accumulators -> B-frag pair IN-LANE.
// pi(32f+8q+j) = 16(2f+(j>>2)) + 4q + (j&3) permutes the k-axis so lane
// (q,l16)'s D-form values {n=16nt+4q+r} ARE its B-frags in register order.
// Weights absorb pi at setup. Cost: 16 fmax + 8 cvt_pk. No shuffles, no LDS.
// ---------------------------------------------------------------------------
__device__ __forceinline__ void repack_relu(const f32x4* v, bf16x8& f0, bf16x8& f1)
{
    union { unsigned u[4]; bf16x8 v8; } A, Bv;
    A.u[0]  = cvt_pk_bf16(fmaxf(v[0][0], 0.f), fmaxf(v[0][1], 0.f));
    A.u[1]  = cvt_pk_bf16(fmaxf(v[0][2], 0.f), fmaxf(v[0][3], 0.f));
    A.u[2]  = cvt_pk_bf16(fmaxf(v[1][0], 0.f), fmaxf(v[1][1], 0.f));
    A.u[3]  = cvt_pk_bf16(fmaxf(v[1][2], 0.f), fmaxf(v[1][3], 0.f));
    Bv.u[0] = cvt_pk_bf16(fmaxf(v[2][0], 0.f), fmaxf(v[2][1], 0.f));
    Bv.u[1] = cvt_pk_bf16(fmaxf(v[2][2], 0.f), fmaxf(v[2][3], 0.f));
    Bv.u[2] = cvt_pk_bf16(fmaxf(v[3][0], 0.f), fmaxf(v[3][1], 0.f));
    Bv.u[3] = cvt_pk_bf16(fmaxf(v[3][2], 0.f), fmaxf(v[3][3], 0.f));
    f0 = A.v8; f1 = Bv.v8;
}

// ---------------------------------------------------------------------------
// Merged setup kernel. r12 CHANGE: Bxt-build reads W_dir/W0 DIRECTLY FROM
// GLOBAL in the inner loop (r0 style: coalesced per-lane columns, L2-hot,
// 8 independent load chains per f -> latency hidden). The r2 33KB LDS stage
// (and r1 register hoist) were never A/B'd vs r0's setup; the total-minus-
// main gap jumped 45->78 µs exactly when they landed. This removes the
// stage, its barrier, and ~1024 per-thread serial LDS reads.
// Kept (verified since r0): zl in LDS, parallel zc (zq), pi-permuted Wat/Wbt,
// natural Bxt rows with XOR swizzle short_idx ^= (row&7)<<3 (rule #21).
// ---------------------------------------------------------------------------
__global__ __launch_bounds__(256)
void setup_kernel(const float* __restrict__ z,
                  const float* __restrict__ W_dir,
                  const float* __restrict__ W0,
                  const float* __restrict__ b0,
                  const float* __restrict__ Wa,
                  const float* __restrict__ Wb,
                  short* __restrict__ Bxt,
                  short* __restrict__ Wat,
                  short* __restrict__ Wbt)
{
    if (blockIdx.x >= 32) {
        int idx = (blockIdx.x - 32) * 256 + threadIdx.x;  // < 5*64*64
        int i = idx >> 12, r = idx & 4095, ks = r >> 6, n = r & 63;
        int f = ks >> 5, q = (ks >> 3) & 3, j = ks & 7;
        int nin = 16 * (2 * f + (j >> 2)) + 4 * q + (j & 3);   // pi(kslot)
        int o   = (i << 12) + (n << 6) + ks;                   // [n_out][kslot]
        int src = (i << 12) + (nin << 6) + n;                  // W[i][nin][n]
        Wat[o] = f2bf(Wa[src]);
        Wbt[o] = f2bf(Wb[src]);
        return;
    }
    const int bc = blockIdx.x;
    const int t  = threadIdx.x & 63;     // output column n (natural row)
    const int g  = threadIdx.x >> 6;     // f-group 0..3
    const float* zb = z + (size_t)bc * F * D;

    __shared__ float zl[F][D];       // 8 KB
    __shared__ float zp[4][D];       // 1 KB
    __shared__ float zq[4][D];       // 1 KB

    for (int i = threadIdx.x; i < F * D; i += 256) zl[i >> 6][i & 63] = zb[i];
    __syncthreads();

    const int sw = (t & 7) << 3;                      // bank swizzle (shorts)
    short* brow = Bxt + ((size_t)bc * 64 + t) * 64;   // natural row = n

    float zi = 0.f;
    for (int f = g * 8; f < g * 8 + 8; ++f) {
        float z0 = 0, z1 = 0, z2 = 0, z3 = 0;
        float a0 = 0, a1 = 0, a2 = 0, a3 = 0;
#pragma unroll
        for (int d = 0; d < D; d += 4) {
            float4 z4 = *(const float4*)&zl[f][d];    // broadcast b128
            z0 += z4.x * W_dir[(d + 0) * D + t];
            z1 += z4.y * W_dir[(d + 1) * D + t];
            z2 += z4.z * W_dir[(d + 2) * D + t];
            z3 += z4.w * W_dir[(d + 3) * D + t];
            a0 += z4.x * W0[(1 + d + 0) * H + t];
            a1 += z4.y * W0[(1 + d + 1) * H + t];
            a2 += z4.z * W0[(1 + d + 2) * H + t];
            a3 += z4.w * W0[(1 + d + 3) * H + t];
        }
        zi += zl[f][t] * ((z0 + z1) + (z2 + z3));
        brow[f ^ sw] = f2bf((a0 + a1) + (a2 + a3));   // ZW row f, col t
    }
    zp[g][t] = zi;
    __syncthreads();
    if (g == 0) {
        float zall = zp[0][t] + zp[1][t] + zp[2][t] + zp[3][t];
        zp[0][t] = zall;                              // full z_inv[t]
    }
    __syncthreads();
    // zc partials: each g-group covers 16 e's
    {
        float zcp = 0.f;
        for (int e = g * 16; e < g * 16 + 16; ++e)
            zcp += zp[0][e] * W0[(65 + e) * H + t];
        zq[g][t] = zcp;
    }
    __syncthreads();
    if (g == 0) {
        brow[32 ^ sw] = f2bf(W0[t]);                  // multiplies s2
        float zc = b0[t] + zq[0][t] + zq[1][t] + zq[2][t] + zq[3][t];
        brow[33 ^ sw] = f2bf(zc);                     // multiplies 1
    } else if (g == 1) {
        for (int k = 34; k < 64; ++k) brow[k ^ sw] = 0;
    }
}

// ---------------------------------------------------------------------------
// Main. r12: EXACTLY r10 (champion, 63.9 µs) — r11's setprio + bias-as-C +
// addr-hoist reverted (measured −2.5 µs net). 4-slot Bxt staging, 4 barriers,
// in-lane repack, swizzled S1 reads, bb0 folded post-loop.
// launch_bounds(256,2): the 128-reg / 4-waves-per-SIMD bucket (r9: crossing
// 128 halves occupancy; <=64 unreachable for this algorithm's state).
// ---------------------------------------------------------------------------
__global__ __launch_bounds__(256, 2)
void main_kernel(const float* __restrict__ p,      // (B,P,3)
                 const float* __restrict__ pos,    // (B,3)
                 const float* __restrict__ W_feat, // (3,F)
                 const short* __restrict__ Bxt,    // (B,C,64n,64k) bf16 (swz)
                 const short* __restrict__ Wat,    // (5,64n,64kslot) pi-perm
                 const short* __restrict__ Wbt,    // (5,64n,64kslot) pi-perm
                 const float* __restrict__ ba,     // (5,H)
                 const float* __restrict__ bb,     // (5,H)
                 const float* __restrict__ Wout,   // (H,1)
                 const float* __restrict__ bout,   // (1,)
                 float* __restrict__ out)          // (B,P)
{
    const int wave = threadIdx.x >> 6;
    const int lane = threadIdx.x & 63;
    const int quad = lane >> 4;
    const int l16  = lane & 15;
    const int b    = blockIdx.y;
    const int base = blockIdx.x * 128 + wave * 32;

    __shared__ __attribute__((aligned(16))) short bxlds[4][4096]; // 32 KB

    const short* bxg = Bxt + (size_t)b * C * 4096;

    // ---- stage channels 0-3 (2 gloads per wave per channel)
#pragma unroll
    for (int c0 = 0; c0 < 4; ++c0) {
        const short* src = bxg + (size_t)c0 * 4096 + (wave * 2) * 512 + lane * 8;
        gload_lds16(src,       &bxlds[c0][(wave * 2) * 512]);
        gload_lds16(src + 512, &bxlds[c0][(wave * 2 + 1) * 512]);
    }

    // ---- point features -> B-frags for both m-tiles
    bf16x8 a0[2], a1[2];
#pragma unroll
    for (int m = 0; m < 2; ++m) {
        const float* pp = p + ((size_t)b * P + base + m * 16 + l16) * 3;
        float px = pp[0] - pos[b * 3 + 0];
        float py = pp[1] - pos[b * 3 + 1];
        float pz = pp[2] - pos[b * 3 + 2];
        float nrm = sqrtf(px * px + py * py + pz * pz);
        if (nrm > 0.5f) { float s = 0.5f / nrm; px *= s; py *= s; pz *= s; }
        float av[8];
        float s2 = 0.f;
#pragma unroll
        for (int j = 0; j < 8; ++j) {
            int k = quad * 8 + j;
            av[j] = px * W_feat[k] + py * W_feat[F + k] + pz * W_feat[2 * F + k];
            s2 += av[j] * av[j];
        }
        s2 += __shfl_xor(s2, 16);
        s2 += __shfl_xor(s2, 32);
        union { bf16x8 v; unsigned u[4]; } ua;
#pragma unroll
        for (int j = 0; j < 4; ++j) ua.u[j] = cvt_pk_bf16(av[2 * j], av[2 * j + 1]);
        a0[m] = ua.v;
        union { bf16x8 v; unsigned u[4]; } ub;
#pragma unroll
        for (int j = 0; j < 4; ++j) ub.u[j] = 0;
        if (quad == 0) ub.u[0] = cvt_pk_bf16(s2, 1.0f);
        a1[m] = ub.v;
    }

    f32x4 pooled[2][4];
#pragma unroll
    for (int m = 0; m < 2; ++m)
#pragma unroll
        for (int nt = 0; nt < 4; ++nt)
            pooled[m][nt] = (f32x4){-1e30f, -1e30f, -1e30f, -1e30f};

    // ---- biases in D-form: n = 16nt + 4q + r  ->  float4 at +16nt+4q
    float4 ba0v[4], bb0v[4];
#pragma unroll
    for (int nt = 0; nt < 4; ++nt) {
        ba0v[nt] = *(const float4*)(ba + nt * 16 + 4 * quad);
        bb0v[nt] = *(const float4*)(bb + nt * 16 + 4 * quad);
    }

    // ---- hoist layer-0 weight A-frags (c-invariant; 64 VGPRs)
    bf16x8 wa0f[4][2], wb0f[4][2];
#pragma unroll
    for (int nt = 0; nt < 4; ++nt) {
        wa0f[nt][0] = *(const bf16x8*)(Wat + (nt * 16 + l16) * 64 + quad * 8);
        wa0f[nt][1] = *(const bf16x8*)(Wat + (nt * 16 + l16) * 64 + 32 + quad * 8);
        wb0f[nt][0] = *(const bf16x8*)(Wbt + (nt * 16 + l16) * 64 + quad * 8);
        wb0f[nt][1] = *(const bf16x8*)(Wbt + (nt * 16 + l16) * 64 + 32 + quad * 8);
    }

    __syncthreads();   // drains vmcnt: bxlds[0..3] published

    // =============== c-loop: 4 barriers total =============================
#pragma unroll 1
    for (int c = 0; c < C; ++c) {
        const short* bxs = &bxlds[c & 3][0];

        // ---- S1: x[n, point] = mfma(A=Bxt rows, B=point-feat frag)
        f32x4 x[2][4];
#pragma unroll
        for (int nt = 0; nt < 4; ++nt) {
            const int row = nt * 16 + l16;
            const int sw  = (row & 7) << 3;
            bf16x8 b0f = *(const bf16x8*)(bxs + row * 64 + ((quad * 8) ^ sw));
            bf16x8 b1f = *(const bf16x8*)(bxs + row * 64 + ((32 + quad * 8) ^ sw));
#pragma unroll
            for (int m = 0; m < 2; ++m) {
                f32x4 acc = (f32x4){0.f, 0.f, 0.f, 0.f};
                acc = __builtin_amdgcn_mfma_f32_16x16x32_bf16(b0f, a0[m], acc, 0, 0, 0);
                acc = __builtin_amdgcn_mfma_f32_16x16x32_bf16(b1f, a1[m], acc, 0, 0, 0);
                x[m][nt] = acc;
            }
        }

        // ---- repack relu(x) -> B-frags (in-lane, zero shuffles)
        bf16x8 xf0[2], xf1[2];
#pragma unroll
        for (int m = 0; m < 2; ++m) repack_relu(x[m], xf0[m], xf1[m]);

        // ---- S2: h = relu(x) @ Wa0 + ba0
        f32x4 h[2][4];
#pragma unroll
        for (int nt = 0; nt < 4; ++nt) {
#pragma unroll
            for (int m = 0; m < 2; ++m) {
                f32x4 acc = (f32x4){ba0v[nt].x, ba0v[nt].y, ba0v[nt].z, ba0v[nt].w};
                acc = __builtin_amdgcn_mfma_f32_16x16x32_bf16(wa0f[nt][0], xf0[m], acc, 0, 0, 0);
                acc = __builtin_amdgcn_mfma_f32_16x16x32_bf16(wa0f[nt][1], xf1[m], acc, 0, 0, 0);
                h[m][nt] = acc;
            }
        }

        // ---- repack relu(h)
        bf16x8 hf0[2], hf1[2];
#pragma unroll
        for (int m = 0; m < 2; ++m) repack_relu(h[m], hf0[m], hf1[m]);

        // ---- S3: x + relu(h) @ Wb0 ; max-pool over c (bb0 folded post-loop)
#pragma unroll
        for (int nt = 0; nt < 4; ++nt) {
#pragma unroll
            for (int m = 0; m < 2; ++m) {
                f32x4 acc = x[m][nt];
                acc = __builtin_amdgcn_mfma_f32_16x16x32_bf16(wb0f[nt][0], hf0[m], acc, 0, 0, 0);
                acc = __builtin_amdgcn_mfma_f32_16x16x32_bf16(wb0f[nt][1], hf1[m], acc, 0, 0, 0);
#pragma unroll
                for (int r = 0; r < 4; ++r)
                    pooled[m][nt][r] = fmaxf(pooled[m][nt][r], acc[r]);
            }
        }

        // ---- barrier schedule: WAR/drain points only
        if (c == 1) {
            __syncthreads();   // all waves past reads of slots 0,1
#pragma unroll
            for (int cc = 4; cc < 6; ++cc) {
                const short* src = bxg + (size_t)cc * 4096 + (wave * 2) * 512 + lane * 8;
                gload_lds16(src,       &bxlds[cc & 3][(wave * 2) * 512]);
                gload_lds16(src + 512, &bxlds[cc & 3][(wave * 2 + 1) * 512]);
            }
        } else if (c == 3) {
            __syncthreads();   // drains ch4/5 gloads; all past reads of s2,s3
#pragma unroll
            for (int cc = 6; cc < 8; ++cc) {
                const short* src = bxg + (size_t)cc * 4096 + (wave * 2) * 512 + lane * 8;
                gload_lds16(src,       &bxlds[cc & 3][(wave * 2) * 512]);
                gload_lds16(src + 512, &bxlds[cc & 3][(wave * 2 + 1) * 512]);
            }
        } else if (c == 5) {
            __syncthreads();   // drains ch6/7 gloads before c=6 reads
        }
    }

    // ---- fold bb0 into pooled once (moved out of the c-loop)
#pragma unroll
    for (int nt = 0; nt < 4; ++nt)
#pragma unroll
        for (int m = 0; m < 2; ++m) {
            pooled[m][nt][0] += bb0v[nt].x;
            pooled[m][nt][1] += bb0v[nt].y;
            pooled[m][nt][2] += bb0v[nt].z;
            pooled[m][nt][3] += bb0v[nt].w;
        }

    // =============== residual blocks 1..4 (2 chains: m-tiles) ===============
#pragma unroll
    for (int i = 1; i < 5; ++i) {
        const short* wa = Wat + i * 4096;
        const short* wb = Wbt + i * 4096;
        float4 bai[4], bbi[4];
#pragma unroll
        for (int nt = 0; nt < 4; ++nt) {
            bai[nt] = *(const float4*)(ba + i * H + nt * 16 + 4 * quad);
            bbi[nt] = *(const float4*)(bb + i * H + nt * 16 + 4 * quad);
        }

        bf16x8 pf0[2], pf1[2];
#pragma unroll
        for (int m = 0; m < 2; ++m) repack_relu(pooled[m], pf0[m], pf1[m]);

        f32x4 h[2][4];
#pragma unroll
        for (int nt = 0; nt < 4; ++nt) {
            bf16x8 w0f = *(const bf16x8*)(wa + (nt * 16 + l16) * 64 + quad * 8);
            bf16x8 w1f = *(const bf16x8*)(wa + (nt * 16 + l16) * 64 + 32 + quad * 8);
#pragma unroll
            for (int m = 0; m < 2; ++m) {
                f32x4 acc = (f32x4){bai[nt].x, bai[nt].y, bai[nt].z, bai[nt].w};
                acc = __builtin_amdgcn_mfma_f32_16x16x32_bf16(w0f, pf0[m], acc, 0, 0, 0);
                acc = __builtin_amdgcn_mfma_f32_16x16x32_bf16(w1f, pf1[m], acc, 0, 0, 0);
                h[m][nt] = acc;
            }
        }

        bf16x8 hf0[2], hf1[2];
#pragma unroll
        for (int m = 0; m < 2; ++m) repack_relu(h[m], hf0[m], hf1[m]);

#pragma unroll
        for (int nt = 0; nt < 4; ++nt) {
            bf16x8 w0f = *(const bf16x8*)(wb + (nt * 16 + l16) * 64 + quad * 8);
            bf16x8 w1f = *(const bf16x8*)(wb + (nt * 16 + l16) * 64 + 32 + quad * 8);
#pragma unroll
            for (int m = 0; m < 2; ++m) {
                f32x4 acc = pooled[m][nt];
                acc[0] += bbi[nt].x; acc[1] += bbi[nt].y;
                acc[2] += bbi[nt].z; acc[3] += bbi[nt].w;
                acc = __builtin_amdgcn_mfma_f32_16x16x32_bf16(w0f, hf0[m], acc, 0, 0, 0);
                acc = __builtin_amdgcn_mfma_f32_16x16x32_bf16(w1f, hf1[m], acc, 0, 0, 0);
                pooled[m][nt] = acc;
            }
        }
    }

    // =============== head: per-lane dot + cross-quad reduce =================
    const float bo = bout[0];
    float4 wo4[4];
#pragma unroll
    for (int nt = 0; nt < 4; ++nt)
        wo4[nt] = *(const float4*)(Wout + nt * 16 + 4 * quad);
#pragma unroll
    for (int m = 0; m < 2; ++m) {
        float s = 0.f;
#pragma unroll
        for (int nt = 0; nt < 4; ++nt) {
            s += fmaxf(pooled[m][nt][0], 0.f) * wo4[nt].x
               + fmaxf(pooled[m][nt][1], 0.f) * wo4[nt].y
               + fmaxf(pooled[m][nt][2], 0.f) * wo4[nt].z
               + fmaxf(pooled[m][nt][3], 0.f) * wo4[nt].w;
        }
        s += __shfl_xor(s, 16);
        s += __shfl_xor(s, 32);
        if (lane < 16)
            out[(size_t)b * P + base + m * 16 + l16] = s + bo;
    }
}

extern "C" void kernel_launch(void* const* d_in, const int* in_sizes, int n_in,
                              void* d_out, int out_size, void* d_ws, size_t ws_size,
                              hipStream_t stream) {
    const float* z      = (const float*)d_in[0];
    const float* pos    = (const float*)d_in[1];
    const float* p      = (const float*)d_in[2];
    const float* W_feat = (const float*)d_in[3];
    const float* W_dir  = (const float*)d_in[4];
    const float* W0     = (const float*)d_in[5];
    const float* b0     = (const float*)d_in[6];
    const float* Wa     = (const float*)d_in[7];
    const float* ba     = (const float*)d_in[8];
    const float* Wb     = (const float*)d_in[9];
    const float* bb     = (const float*)d_in[10];
    const float* Wout   = (const float*)d_in[11];
    const float* bout   = (const float*)d_in[12];
    float* out = (float*)d_out;

    short* wsS = (short*)d_ws;
    short* Bxt = wsS;                    // B*C*64*64 shorts
    short* Wat = wsS + 32 * 4096;        // 5*4096
    short* Wbt = Wat + 5 * 4096;         // 5*4096

    setup_kernel<<<112, 256, 0, stream>>>(z, W_dir, W0, b0, Wa, Wb, Bxt, Wat, Wbt);

    dim3 grid(P / 128, B);
    main_kernel<<<grid, 256, 0, stream>>>(p, pos, W_feat, Bxt, Wat, Wbt,
                                          ba, bb, Wout, bout, out);
}

// Round 13
// 139.709 us; speedup vs baseline: 1.0331x; 1.0203x over previous
//
#include <hip/hip_runtime.h>
#include <math.h>

#define B 4
#define P 32768
#define C 8
#define F 32
#define D 64
#define H 64

typedef __attribute__((ext_vector_type(8))) short bf16x8;
typedef __attribute__((ext_vector_type(4))) float f32x4;

__device__ __forceinline__ short f2bf(float f) {
    union { float f; unsigned u; } v; v.f = f;
    unsigned r = (v.u + 0x7FFFu + ((v.u >> 16) & 1u)) >> 16;   // RNE
    return (short)r;
}

// packed f32x2 -> bf16x2 (RNE) in one VALU op
__device__ __forceinline__ unsigned cvt_pk_bf16(float lo, float hi) {
    unsigned r;
    asm("v_cvt_pk_bf16_f32 %0, %1, %2" : "=v"(r) : "v"(lo), "v"(hi));
    return r;
}

// async global->LDS, 16B per lane. LDS dest = wave-uniform base + lane*16;
// global src = per-lane address (guide §5).
__device__ __forceinline__ void gload_lds16(const void* g, void* s) {
    __builtin_amdgcn_global_load_lds(
        (const __attribute__((address_space(1))) unsigned*)g,
        (__attribute__((address_space(3))) unsigned*)s, 16, 0, 0);
}

// ---------------------------------------------------------------------------
// repack_relu (r7, verified): D-form accumulators -> B-frag pair IN-LANE.
// pi(32f+8q+j) = 16(2f+(j>>2)) + 4q + (j&3) permutes the k-axis so lane
// (q,l16)'s D-form values {n=16nt+4q+r} ARE its B-frags in register order.
// Weights absorb pi at setup. Cost: 16 fmax + 8 cvt_pk. No shuffles, no LDS.
// ---------------------------------------------------------------------------
__device__ __forceinline__ void repack_relu(const f32x4* v, bf16x8& f0, bf16x8& f1)
{
    union { unsigned u[4]; bf16x8 v8; } A, Bv;
    A.u[0]  = cvt_pk_bf16(fmaxf(v[0][0], 0.f), fmaxf(v[0][1], 0.f));
    A.u[1]  = cvt_pk_bf16(fmaxf(v[0][2], 0.f), fmaxf(v[0][3], 0.f));
    A.u[2]  = cvt_pk_bf16(fmaxf(v[1][0], 0.f), fmaxf(v[1][1], 0.f));
    A.u[3]  = cvt_pk_bf16(fmaxf(v[1][2], 0.f), fmaxf(v[1][3], 0.f));
    Bv.u[0] = cvt_pk_bf16(fmaxf(v[2][0], 0.f), fmaxf(v[2][1], 0.f));
    Bv.u[1] = cvt_pk_bf16(fmaxf(v[2][2], 0.f), fmaxf(v[2][3], 0.f));
    Bv.u[2] = cvt_pk_bf16(fmaxf(v[3][0], 0.f), fmaxf(v[3][1], 0.f));
    Bv.u[3] = cvt_pk_bf16(fmaxf(v[3][2], 0.f), fmaxf(v[3][3], 0.f));
    f0 = A.v8; f1 = Bv.v8;
}

// ---------------------------------------------------------------------------
// Merged setup kernel. r13 CHANGE: Bxt shrinks to (B,C,64n,32k) — ONLY the
// ZW rows (features f=0..31). The former rows 32 (W0 row 0, multiplies s2)
// and 33 (zc, multiplies 1) leave the MFMA: W0 row 0 is read directly from
// global by main (c-invariant), and zc goes to a small f32 array zcA[b][c][n]
// (more precise than the old bf16 path). Swizzle for 64B rows:
// short_idx ^= (n&3)<<3 (verified even bank spread for main's b128 reads).
// Wa/Wb pi-permutation and direct-global W_dir/W0 reads (r12): unchanged.
// ---------------------------------------------------------------------------
__global__ __launch_bounds__(256)
void setup_kernel(const float* __restrict__ z,
                  const float* __restrict__ W_dir,
                  const float* __restrict__ W0,
                  const float* __restrict__ b0,
                  const float* __restrict__ Wa,
                  const float* __restrict__ Wb,
                  short* __restrict__ Bxt,
                  short* __restrict__ Wat,
                  short* __restrict__ Wbt,
                  float* __restrict__ zcA)
{
    if (blockIdx.x >= 32) {
        int idx = (blockIdx.x - 32) * 256 + threadIdx.x;  // < 5*64*64
        int i = idx >> 12, r = idx & 4095, ks = r >> 6, n = r & 63;
        int f = ks >> 5, q = (ks >> 3) & 3, j = ks & 7;
        int nin = 16 * (2 * f + (j >> 2)) + 4 * q + (j & 3);   // pi(kslot)
        int o   = (i << 12) + (n << 6) + ks;                   // [n_out][kslot]
        int src = (i << 12) + (nin << 6) + n;                  // W[i][nin][n]
        Wat[o] = f2bf(Wa[src]);
        Wbt[o] = f2bf(Wb[src]);
        return;
    }
    const int bc = blockIdx.x;
    const int t  = threadIdx.x & 63;     // output column n (natural row)
    const int g  = threadIdx.x >> 6;     // f-group 0..3
    const float* zb = z + (size_t)bc * F * D;

    __shared__ float zl[F][D];       // 8 KB
    __shared__ float zp[4][D];       // 1 KB
    __shared__ float zq[4][D];       // 1 KB

    for (int i = threadIdx.x; i < F * D; i += 256) zl[i >> 6][i & 63] = zb[i];
    __syncthreads();

    const int sw = (t & 3) << 3;                      // bank swizzle (shorts)
    short* brow = Bxt + ((size_t)bc * 64 + t) * 32;   // natural row = n, 32k

    float zi = 0.f;
    for (int f = g * 8; f < g * 8 + 8; ++f) {
        float z0 = 0, z1 = 0, z2 = 0, z3 = 0;
        float a0 = 0, a1 = 0, a2 = 0, a3 = 0;
#pragma unroll
        for (int d = 0; d < D; d += 4) {
            float4 z4 = *(const float4*)&zl[f][d];    // broadcast b128
            z0 += z4.x * W_dir[(d + 0) * D + t];
            z1 += z4.y * W_dir[(d + 1) * D + t];
            z2 += z4.z * W_dir[(d + 2) * D + t];
            z3 += z4.w * W_dir[(d + 3) * D + t];
            a0 += z4.x * W0[(1 + d + 0) * H + t];
            a1 += z4.y * W0[(1 + d + 1) * H + t];
            a2 += z4.z * W0[(1 + d + 2) * H + t];
            a3 += z4.w * W0[(1 + d + 3) * H + t];
        }
        zi += zl[f][t] * ((z0 + z1) + (z2 + z3));
        brow[f ^ sw] = f2bf((a0 + a1) + (a2 + a3));   // ZW row f, col t
    }
    zp[g][t] = zi;
    __syncthreads();
    if (g == 0) {
        float zall = zp[0][t] + zp[1][t] + zp[2][t] + zp[3][t];
        zp[0][t] = zall;                              // full z_inv[t]
    }
    __syncthreads();
    // zc partials: each g-group covers 16 e's
    {
        float zcp = 0.f;
        for (int e = g * 16; e < g * 16 + 16; ++e)
            zcp += zp[0][e] * W0[(65 + e) * H + t];
        zq[g][t] = zcp;
    }
    __syncthreads();
    if (g == 0) {
        float zc = b0[t] + zq[0][t] + zq[1][t] + zq[2][t] + zq[3][t];
        zcA[bc * 64 + t] = zc;                        // f32 (was bf16 row 33)
    }
}

// ---------------------------------------------------------------------------
// Main. r13: K=32 S1 + rank-2 VALU fold + ZERO in-loop barriers.
// (1) S1 is ONE K=32 MFMA per (m,nt): acc = mfma(ZWrows, feat, C=zcq[nt]),
//     then x += s2[m]*w32[n] (32 v_fmac/iter). Removes the all-but-zero
//     second K-half (8 MFMAs + 4 ds_reads per iter spent on 2 nonzero slots).
// (2) Halved tiles -> ALL 8 channels fit in 32 KB LDS: staged once in the
//     preamble, ONE barrier total. The c-loop has no syncs -> the 4 waves
//     de-phase, decorrelating the S1 LDS-wait stalls that r12's counters
//     implicated in the ~40% all-idle issue slots.
// (3) Swizzle for 64B rows: byte ^= ((row&3)<<4) both sides (setup writes
//     pre-swizzled global; gload_lds is linear; reads apply same XOR).
// Register budget: -a1(8) - bb0v deferred post-loop(16) + w32q(16) + s2m(2).
// Gates: VGPR <= 128, WRITE ~512 KB, SQ_LDS_BANK_CONFLICT ~0.
// launch_bounds(256,2): the 128-reg / 4-waves-per-SIMD bucket.
// ---------------------------------------------------------------------------
__global__ __launch_bounds__(256, 2)
void main_kernel(const float* __restrict__ p,      // (B,P,3)
                 const float* __restrict__ pos,    // (B,3)
                 const float* __restrict__ W_feat, // (3,F)
                 const float* __restrict__ W0,     // (1+2D,H) — row 0 used
                 const short* __restrict__ Bxt,    // (B,C,64n,32k) bf16 (swz)
                 const short* __restrict__ Wat,    // (5,64n,64kslot) pi-perm
                 const short* __restrict__ Wbt,    // (5,64n,64kslot) pi-perm
                 const float* __restrict__ zcA,    // (B,C,64) f32
                 const float* __restrict__ ba,     // (5,H)
                 const float* __restrict__ bb,     // (5,H)
                 const float* __restrict__ Wout,   // (H,1)
                 const float* __restrict__ bout,   // (1,)
                 float* __restrict__ out)          // (B,P)
{
    const int wave = threadIdx.x >> 6;
    const int lane = threadIdx.x & 63;
    const int quad = lane >> 4;
    const int l16  = lane & 15;
    const int b    = blockIdx.y;
    const int base = blockIdx.x * 128 + wave * 32;

    __shared__ __attribute__((aligned(16))) short bxlds[8][2048]; // 32 KB

    const short* bxg = Bxt + (size_t)b * C * 2048;

    // ---- stage ALL 8 channels (1 gload per wave per channel; in flight
    //      under the whole preamble; drained by the single barrier)
#pragma unroll
    for (int c0 = 0; c0 < 8; ++c0) {
        const short* src = bxg + (size_t)c0 * 2048 + wave * 512 + lane * 8;
        gload_lds16(src, &bxlds[c0][wave * 512]);
    }

    // ---- point features -> B-frag (K=32: lane (q,l16) holds point l16's
    //      feature k = 8q+j) + per-point invariant s2
    bf16x8 a0[2];
    float s2m[2];
#pragma unroll
    for (int m = 0; m < 2; ++m) {
        const float* pp = p + ((size_t)b * P + base + m * 16 + l16) * 3;
        float px = pp[0] - pos[b * 3 + 0];
        float py = pp[1] - pos[b * 3 + 1];
        float pz = pp[2] - pos[b * 3 + 2];
        float nrm = sqrtf(px * px + py * py + pz * pz);
        if (nrm > 0.5f) { float s = 0.5f / nrm; px *= s; py *= s; pz *= s; }
        float av[8];
        float s2 = 0.f;
#pragma unroll
        for (int j = 0; j < 8; ++j) {
            int k = quad * 8 + j;
            av[j] = px * W_feat[k] + py * W_feat[F + k] + pz * W_feat[2 * F + k];
            s2 += av[j] * av[j];
        }
        s2 += __shfl_xor(s2, 16);
        s2 += __shfl_xor(s2, 32);
        s2m[m] = s2;
        union { bf16x8 v; unsigned u[4]; } ua;
#pragma unroll
        for (int j = 0; j < 4; ++j) ua.u[j] = cvt_pk_bf16(av[2 * j], av[2 * j + 1]);
        a0[m] = ua.v;
    }

    f32x4 pooled[2][4];
#pragma unroll
    for (int m = 0; m < 2; ++m)
#pragma unroll
        for (int nt = 0; nt < 4; ++nt)
            pooled[m][nt] = (f32x4){-1e30f, -1e30f, -1e30f, -1e30f};

    // ---- c-invariant vectors in D-form quads (n = 16nt + 4q + r)
    f32x4 ba0q[4], w32q[4];
#pragma unroll
    for (int nt = 0; nt < 4; ++nt) {
        ba0q[nt] = *(const f32x4*)(ba + nt * 16 + 4 * quad);
        w32q[nt] = *(const f32x4*)(W0 + nt * 16 + 4 * quad);   // W0 row 0
    }

    // ---- hoist layer-0 weight A-frags (c-invariant; 64 VGPRs)
    bf16x8 wa0f[4][2], wb0f[4][2];
#pragma unroll
    for (int nt = 0; nt < 4; ++nt) {
        wa0f[nt][0] = *(const bf16x8*)(Wat + (nt * 16 + l16) * 64 + quad * 8);
        wa0f[nt][1] = *(const bf16x8*)(Wat + (nt * 16 + l16) * 64 + 32 + quad * 8);
        wb0f[nt][0] = *(const bf16x8*)(Wbt + (nt * 16 + l16) * 64 + quad * 8);
        wb0f[nt][1] = *(const bf16x8*)(Wbt + (nt * 16 + l16) * 64 + 32 + quad * 8);
    }

    __syncthreads();   // the ONLY barrier: drains vmcnt, publishes bxlds[0..7]

    const float* zcb = zcA + (size_t)b * C * 64;

    // =============== c-loop: ZERO barriers, waves de-phase ==================
#pragma unroll 1
    for (int c = 0; c < C; ++c) {
        const short* bxs = &bxlds[c][0];

        // ---- per-channel zc quads (L2-hot; issued before S1's ds_reads)
        f32x4 zcq[4];
#pragma unroll
        for (int nt = 0; nt < 4; ++nt)
            zcq[nt] = *(const f32x4*)(zcb + c * 64 + nt * 16 + 4 * quad);

        // ---- S1: x = mfma(ZWrows, feat, C=zc) + s2*w32 (rank-2 VALU fold)
        f32x4 x[2][4];
#pragma unroll
        for (int nt = 0; nt < 4; ++nt) {
            const int row = nt * 16 + l16;
            const int sw  = (row & 3) << 3;
            bf16x8 b0f = *(const bf16x8*)(bxs + row * 32 + ((quad * 8) ^ sw));
#pragma unroll
            for (int m = 0; m < 2; ++m) {
                f32x4 acc = __builtin_amdgcn_mfma_f32_16x16x32_bf16(b0f, a0[m], zcq[nt], 0, 0, 0);
#pragma unroll
                for (int r = 0; r < 4; ++r) acc[r] += s2m[m] * w32q[nt][r];
                x[m][nt] = acc;
            }
        }

        // ---- repack relu(x) -> B-frags (in-lane, zero shuffles)
        bf16x8 xf0[2], xf1[2];
#pragma unroll
        for (int m = 0; m < 2; ++m) repack_relu(x[m], xf0[m], xf1[m]);

        // ---- S2: h = relu(x) @ Wa0 + ba0
        f32x4 h[2][4];
#pragma unroll
        for (int nt = 0; nt < 4; ++nt) {
#pragma unroll
            for (int m = 0; m < 2; ++m) {
                f32x4 acc = __builtin_amdgcn_mfma_f32_16x16x32_bf16(wa0f[nt][0], xf0[m], ba0q[nt], 0, 0, 0);
                acc = __builtin_amdgcn_mfma_f32_16x16x32_bf16(wa0f[nt][1], xf1[m], acc, 0, 0, 0);
                h[m][nt] = acc;
            }
        }

        // ---- repack relu(h)
        bf16x8 hf0[2], hf1[2];
#pragma unroll
        for (int m = 0; m < 2; ++m) repack_relu(h[m], hf0[m], hf1[m]);

        // ---- S3: x + relu(h) @ Wb0 ; max-pool over c (bb0 folded post-loop)
#pragma unroll
        for (int nt = 0; nt < 4; ++nt) {
#pragma unroll
            for (int m = 0; m < 2; ++m) {
                f32x4 acc = __builtin_amdgcn_mfma_f32_16x16x32_bf16(wb0f[nt][0], hf0[m], x[m][nt], 0, 0, 0);
                acc = __builtin_amdgcn_mfma_f32_16x16x32_bf16(wb0f[nt][1], hf1[m], acc, 0, 0, 0);
#pragma unroll
                for (int r = 0; r < 4; ++r)
                    pooled[m][nt][r] = fmaxf(pooled[m][nt][r], acc[r]);
            }
        }
    }

    // ---- fold bb0 into pooled once (bb0 loaded HERE: 16 regs not live
    //      through the c-loop)
    {
        f32x4 bb0q[4];
#pragma unroll
        for (int nt = 0; nt < 4; ++nt)
            bb0q[nt] = *(const f32x4*)(bb + nt * 16 + 4 * quad);
#pragma unroll
        for (int nt = 0; nt < 4; ++nt)
#pragma unroll
            for (int m = 0; m < 2; ++m)
#pragma unroll
                for (int r = 0; r < 4; ++r)
                    pooled[m][nt][r] += bb0q[nt][r];
    }

    // =============== residual blocks 1..4 (2 chains: m-tiles) ===============
#pragma unroll
    for (int i = 1; i < 5; ++i) {
        const short* wa = Wat + i * 4096;
        const short* wb = Wbt + i * 4096;
        float4 bai[4], bbi[4];
#pragma unroll
        for (int nt = 0; nt < 4; ++nt) {
            bai[nt] = *(const float4*)(ba + i * H + nt * 16 + 4 * quad);
            bbi[nt] = *(const float4*)(bb + i * H + nt * 16 + 4 * quad);
        }

        bf16x8 pf0[2], pf1[2];
#pragma unroll
        for (int m = 0; m < 2; ++m) repack_relu(pooled[m], pf0[m], pf1[m]);

        f32x4 h[2][4];
#pragma unroll
        for (int nt = 0; nt < 4; ++nt) {
            bf16x8 w0f = *(const bf16x8*)(wa + (nt * 16 + l16) * 64 + quad * 8);
            bf16x8 w1f = *(const bf16x8*)(wa + (nt * 16 + l16) * 64 + 32 + quad * 8);
#pragma unroll
            for (int m = 0; m < 2; ++m) {
                f32x4 acc = (f32x4){bai[nt].x, bai[nt].y, bai[nt].z, bai[nt].w};
                acc = __builtin_amdgcn_mfma_f32_16x16x32_bf16(w0f, pf0[m], acc, 0, 0, 0);
                acc = __builtin_amdgcn_mfma_f32_16x16x32_bf16(w1f, pf1[m], acc, 0, 0, 0);
                h[m][nt] = acc;
            }
        }

        bf16x8 hf0[2], hf1[2];
#pragma unroll
        for (int m = 0; m < 2; ++m) repack_relu(h[m], hf0[m], hf1[m]);

#pragma unroll
        for (int nt = 0; nt < 4; ++nt) {
            bf16x8 w0f = *(const bf16x8*)(wb + (nt * 16 + l16) * 64 + quad * 8);
            bf16x8 w1f = *(const bf16x8*)(wb + (nt * 16 + l16) * 64 + 32 + quad * 8);
#pragma unroll
            for (int m = 0; m < 2; ++m) {
                f32x4 acc = pooled[m][nt];
                acc[0] += bbi[nt].x; acc[1] += bbi[nt].y;
                acc[2] += bbi[nt].z; acc[3] += bbi[nt].w;
                acc = __builtin_amdgcn_mfma_f32_16x16x32_bf16(w0f, hf0[m], acc, 0, 0, 0);
                acc = __builtin_amdgcn_mfma_f32_16x16x32_bf16(w1f, hf1[m], acc, 0, 0, 0);
                pooled[m][nt] = acc;
            }
        }
    }

    // =============== head: per-lane dot + cross-quad reduce =================
    const float bo = bout[0];
    float4 wo4[4];
#pragma unroll
    for (int nt = 0; nt < 4; ++nt)
        wo4[nt] = *(const float4*)(Wout + nt * 16 + 4 * quad);
#pragma unroll
    for (int m = 0; m < 2; ++m) {
        float s = 0.f;
#pragma unroll
        for (int nt = 0; nt < 4; ++nt) {
            s += fmaxf(pooled[m][nt][0], 0.f) * wo4[nt].x
               + fmaxf(pooled[m][nt][1], 0.f) * wo4[nt].y
               + fmaxf(pooled[m][nt][2], 0.f) * wo4[nt].z
               + fmaxf(pooled[m][nt][3], 0.f) * wo4[nt].w;
        }
        s += __shfl_xor(s, 16);
        s += __shfl_xor(s, 32);
        if (lane < 16)
            out[(size_t)b * P + base + m * 16 + l16] = s + bo;
    }
}

extern "C" void kernel_launch(void* const* d_in, const int* in_sizes, int n_in,
                              void* d_out, int out_size, void* d_ws, size_t ws_size,
                              hipStream_t stream) {
    const float* z      = (const float*)d_in[0];
    const float* pos    = (const float*)d_in[1];
    const float* p      = (const float*)d_in[2];
    const float* W_feat = (const float*)d_in[3];
    const float* W_dir  = (const float*)d_in[4];
    const float* W0     = (const float*)d_in[5];
    const float* b0     = (const float*)d_in[6];
    const float* Wa     = (const float*)d_in[7];
    const float* ba     = (const float*)d_in[8];
    const float* Wb     = (const float*)d_in[9];
    const float* bb     = (const float*)d_in[10];
    const float* Wout   = (const float*)d_in[11];
    const float* bout   = (const float*)d_in[12];
    float* out = (float*)d_out;

    short* wsS = (short*)d_ws;
    short* Bxt = wsS;                     // B*C*64*32 shorts = 65536
    short* Wat = wsS + 32 * 2048;         // 5*4096
    short* Wbt = Wat + 5 * 4096;          // 5*4096
    float* zcA = (float*)(Wbt + 5 * 4096);// B*C*64 floats (16B-aligned)

    setup_kernel<<<112, 256, 0, stream>>>(z, W_dir, W0, b0, Wa, Wb,
                                          Bxt, Wat, Wbt, zcA);

    dim3 grid(P / 128, B);
    main_kernel<<<grid, 256, 0, stream>>>(p, pos, W_feat, W0, Bxt, Wat, Wbt,
                                          zcA, ba, bb, Wout, bout, out);
}

// Round 14
// 135.772 us; speedup vs baseline: 1.0630x; 1.0290x over previous
//
#include <hip/hip_runtime.h>
#include <math.h>

#define B 4
#define P 32768
#define C 8
#define F 32
#define D 64
#define H 64

typedef __attribute__((ext_vector_type(8))) short bf16x8;
typedef __attribute__((ext_vector_type(4))) float f32x4;

__device__ __forceinline__ short f2bf(float f) {
    union { float f; unsigned u; } v; v.f = f;
    unsigned r = (v.u + 0x7FFFu + ((v.u >> 16) & 1u)) >> 16;   // RNE
    return (short)r;
}

// packed f32x2 -> bf16x2 (RNE) in one VALU op
__device__ __forceinline__ unsigned cvt_pk_bf16(float lo, float hi) {
    unsigned r;
    asm("v_cvt_pk_bf16_f32 %0, %1, %2" : "=v"(r) : "v"(lo), "v"(hi));
    return r;
}

// async global->LDS, 16B per lane. LDS dest = wave-uniform base + lane*16;
// global src = per-lane address (guide §5).
__device__ __forceinline__ void gload_lds16(const void* g, void* s) {
    __builtin_amdgcn_global_load_lds(
        (const __attribute__((address_space(1))) unsigned*)g,
        (__attribute__((address_space(3))) unsigned*)s, 16, 0, 0);
}

// ---------------------------------------------------------------------------
// repack_relu (r7, verified): D-form accumulators -> B-frag pair IN-LANE.
// pi(32f+8q+j) = 16(2f+(j>>2)) + 4q + (j&3) permutes the k-axis so lane
// (q,l16)'s D-form values {n=16nt+4q+r} ARE its B-frags in register order.
// Weights absorb pi at setup. Cost: 16 fmax + 8 cvt_pk. No shuffles, no LDS.
// ---------------------------------------------------------------------------
__device__ __forceinline__ void repack_relu(const f32x4* v, bf16x8& f0, bf16x8& f1)
{
    union { unsigned u[4]; bf16x8 v8; } A, Bv;
    A.u[0]  = cvt_pk_bf16(fmaxf(v[0][0], 0.f), fmaxf(v[0][1], 0.f));
    A.u[1]  = cvt_pk_bf16(fmaxf(v[0][2], 0.f), fmaxf(v[0][3], 0.f));
    A.u[2]  = cvt_pk_bf16(fmaxf(v[1][0], 0.f), fmaxf(v[1][1], 0.f));
    A.u[3]  = cvt_pk_bf16(fmaxf(v[1][2], 0.f), fmaxf(v[1][3], 0.f));
    Bv.u[0] = cvt_pk_bf16(fmaxf(v[2][0], 0.f), fmaxf(v[2][1], 0.f));
    Bv.u[1] = cvt_pk_bf16(fmaxf(v[2][2], 0.f), fmaxf(v[2][3], 0.f));
    Bv.u[2] = cvt_pk_bf16(fmaxf(v[3][0], 0.f), fmaxf(v[3][1], 0.f));
    Bv.u[3] = cvt_pk_bf16(fmaxf(v[3][2], 0.f), fmaxf(v[3][3], 0.f));
    f0 = A.v8; f1 = Bv.v8;
}

// ---------------------------------------------------------------------------
// Merged setup kernel. r14 CHANGE vs r13: Bxt swizzle is X(row)=(row>>1)&3
// (short_idx ^= ((row>>1)&3)<<3). r13's (row&3) gave the 8 consecutive lanes
// of an LDS service group only 4 of 8 bank-slots (slot = (row&1, q^X)) ->
// 2-way serialization, 524K conflict cycles. (row>>1)&3 makes rows r..r+7
// at fixed q cover all 8 slots -> conflict-free. Everything else = r13:
// Bxt (B,C,64n,32k) ZW rows only, zcA f32 sideband, pi-permuted Wa/Wb,
// direct-global W_dir/W0 reads.
// ---------------------------------------------------------------------------
__global__ __launch_bounds__(256)
void setup_kernel(const float* __restrict__ z,
                  const float* __restrict__ W_dir,
                  const float* __restrict__ W0,
                  const float* __restrict__ b0,
                  const float* __restrict__ Wa,
                  const float* __restrict__ Wb,
                  short* __restrict__ Bxt,
                  short* __restrict__ Wat,
                  short* __restrict__ Wbt,
                  float* __restrict__ zcA)
{
    if (blockIdx.x >= 32) {
        int idx = (blockIdx.x - 32) * 256 + threadIdx.x;  // < 5*64*64
        int i = idx >> 12, r = idx & 4095, ks = r >> 6, n = r & 63;
        int f = ks >> 5, q = (ks >> 3) & 3, j = ks & 7;
        int nin = 16 * (2 * f + (j >> 2)) + 4 * q + (j & 3);   // pi(kslot)
        int o   = (i << 12) + (n << 6) + ks;                   // [n_out][kslot]
        int src = (i << 12) + (nin << 6) + n;                  // W[i][nin][n]
        Wat[o] = f2bf(Wa[src]);
        Wbt[o] = f2bf(Wb[src]);
        return;
    }
    const int bc = blockIdx.x;
    const int t  = threadIdx.x & 63;     // output column n (natural row)
    const int g  = threadIdx.x >> 6;     // f-group 0..3
    const float* zb = z + (size_t)bc * F * D;

    __shared__ float zl[F][D];       // 8 KB
    __shared__ float zp[4][D];       // 1 KB
    __shared__ float zq[4][D];       // 1 KB

    for (int i = threadIdx.x; i < F * D; i += 256) zl[i >> 6][i & 63] = zb[i];
    __syncthreads();

    const int sw = ((t >> 1) & 3) << 3;               // r14 swizzle (shorts)
    short* brow = Bxt + ((size_t)bc * 64 + t) * 32;   // natural row = n, 32k

    float zi = 0.f;
    for (int f = g * 8; f < g * 8 + 8; ++f) {
        float z0 = 0, z1 = 0, z2 = 0, z3 = 0;
        float a0 = 0, a1 = 0, a2 = 0, a3 = 0;
#pragma unroll
        for (int d = 0; d < D; d += 4) {
            float4 z4 = *(const float4*)&zl[f][d];    // broadcast b128
            z0 += z4.x * W_dir[(d + 0) * D + t];
            z1 += z4.y * W_dir[(d + 1) * D + t];
            z2 += z4.z * W_dir[(d + 2) * D + t];
            z3 += z4.w * W_dir[(d + 3) * D + t];
            a0 += z4.x * W0[(1 + d + 0) * H + t];
            a1 += z4.y * W0[(1 + d + 1) * H + t];
            a2 += z4.z * W0[(1 + d + 2) * H + t];
            a3 += z4.w * W0[(1 + d + 3) * H + t];
        }
        zi += zl[f][t] * ((z0 + z1) + (z2 + z3));
        brow[f ^ sw] = f2bf((a0 + a1) + (a2 + a3));   // ZW row f, col t
    }
    zp[g][t] = zi;
    __syncthreads();
    if (g == 0) {
        float zall = zp[0][t] + zp[1][t] + zp[2][t] + zp[3][t];
        zp[0][t] = zall;                              // full z_inv[t]
    }
    __syncthreads();
    // zc partials: each g-group covers 16 e's
    {
        float zcp = 0.f;
        for (int e = g * 16; e < g * 16 + 16; ++e)
            zcp += zp[0][e] * W0[(65 + e) * H + t];
        zq[g][t] = zcp;
    }
    __syncthreads();
    if (g == 0) {
        float zc = b0[t] + zq[0][t] + zq[1][t] + zq[2][t] + zq[3][t];
        zcA[bc * 64 + t] = zc;                        // f32 (was bf16 row 33)
    }
}

// ---------------------------------------------------------------------------
// Main. r14: r13's K=32 / zero-in-loop-barrier structure with the two
// defects fixed:
// (1) S1 swizzle X(row)=(row>>1)&3 (matches setup) -> conflict-free b128.
// (2) zc staged into LDS (2 KB, preamble, covered by the single barrier);
//     in-loop zcq is a quad-uniform LDS broadcast read (~30 cy, overlapped)
//     instead of r13's serial GLOBAL load feeding the MFMA C-operand
//     (~200+ cy on the critical path at the top of every iteration).
// Gates: VGPR <= 128, WRITE ~512 KB, SQ_LDS_BANK_CONFLICT ~0.
// launch_bounds(256,2): the 128-reg / 4-waves-per-SIMD bucket.
// ---------------------------------------------------------------------------
__global__ __launch_bounds__(256, 2)
void main_kernel(const float* __restrict__ p,      // (B,P,3)
                 const float* __restrict__ pos,    // (B,3)
                 const float* __restrict__ W_feat, // (3,F)
                 const float* __restrict__ W0,     // (1+2D,H) — row 0 used
                 const short* __restrict__ Bxt,    // (B,C,64n,32k) bf16 (swz)
                 const short* __restrict__ Wat,    // (5,64n,64kslot) pi-perm
                 const short* __restrict__ Wbt,    // (5,64n,64kslot) pi-perm
                 const float* __restrict__ zcA,    // (B,C,64) f32
                 const float* __restrict__ ba,     // (5,H)
                 const float* __restrict__ bb,     // (5,H)
                 const float* __restrict__ Wout,   // (H,1)
                 const float* __restrict__ bout,   // (1,)
                 float* __restrict__ out)          // (B,P)
{
    const int wave = threadIdx.x >> 6;
    const int lane = threadIdx.x & 63;
    const int quad = lane >> 4;
    const int l16  = lane & 15;
    const int b    = blockIdx.y;
    const int base = blockIdx.x * 128 + wave * 32;

    __shared__ __attribute__((aligned(16))) short bxlds[8][2048]; // 32 KB
    __shared__ __attribute__((aligned(16))) float zclds[C][64];   // 2 KB

    const short* bxg = Bxt + (size_t)b * C * 2048;
    const float* zcb = zcA + (size_t)b * C * 64;

    // ---- stage ALL 8 channels + zc sideband (in flight under the whole
    //      preamble; drained by the single barrier)
#pragma unroll
    for (int c0 = 0; c0 < 8; ++c0) {
        const short* src = bxg + (size_t)c0 * 2048 + wave * 512 + lane * 8;
        gload_lds16(src, &bxlds[c0][wave * 512]);
    }
    if (wave < 2)
        gload_lds16(zcb + wave * 256 + lane * 4, &zclds[0][0] + wave * 256);

    // ---- point features -> B-frag (K=32) + per-point invariant s2
    bf16x8 a0[2];
    float s2m[2];
#pragma unroll
    for (int m = 0; m < 2; ++m) {
        const float* pp = p + ((size_t)b * P + base + m * 16 + l16) * 3;
        float px = pp[0] - pos[b * 3 + 0];
        float py = pp[1] - pos[b * 3 + 1];
        float pz = pp[2] - pos[b * 3 + 2];
        float nrm = sqrtf(px * px + py * py + pz * pz);
        if (nrm > 0.5f) { float s = 0.5f / nrm; px *= s; py *= s; pz *= s; }
        float av[8];
        float s2 = 0.f;
#pragma unroll
        for (int j = 0; j < 8; ++j) {
            int k = quad * 8 + j;
            av[j] = px * W_feat[k] + py * W_feat[F + k] + pz * W_feat[2 * F + k];
            s2 += av[j] * av[j];
        }
        s2 += __shfl_xor(s2, 16);
        s2 += __shfl_xor(s2, 32);
        s2m[m] = s2;
        union { bf16x8 v; unsigned u[4]; } ua;
#pragma unroll
        for (int j = 0; j < 4; ++j) ua.u[j] = cvt_pk_bf16(av[2 * j], av[2 * j + 1]);
        a0[m] = ua.v;
    }

    f32x4 pooled[2][4];
#pragma unroll
    for (int m = 0; m < 2; ++m)
#pragma unroll
        for (int nt = 0; nt < 4; ++nt)
            pooled[m][nt] = (f32x4){-1e30f, -1e30f, -1e30f, -1e30f};

    // ---- c-invariant vectors in D-form quads (n = 16nt + 4q + r)
    f32x4 ba0q[4], w32q[4];
#pragma unroll
    for (int nt = 0; nt < 4; ++nt) {
        ba0q[nt] = *(const f32x4*)(ba + nt * 16 + 4 * quad);
        w32q[nt] = *(const f32x4*)(W0 + nt * 16 + 4 * quad);   // W0 row 0
    }

    // ---- hoist layer-0 weight A-frags (c-invariant; 64 VGPRs)
    bf16x8 wa0f[4][2], wb0f[4][2];
#pragma unroll
    for (int nt = 0; nt < 4; ++nt) {
        wa0f[nt][0] = *(const bf16x8*)(Wat + (nt * 16 + l16) * 64 + quad * 8);
        wa0f[nt][1] = *(const bf16x8*)(Wat + (nt * 16 + l16) * 64 + 32 + quad * 8);
        wb0f[nt][0] = *(const bf16x8*)(Wbt + (nt * 16 + l16) * 64 + quad * 8);
        wb0f[nt][1] = *(const bf16x8*)(Wbt + (nt * 16 + l16) * 64 + 32 + quad * 8);
    }

    __syncthreads();   // the ONLY barrier: drains vmcnt, publishes LDS

    // =============== c-loop: ZERO barriers, waves de-phase ==================
#pragma unroll 1
    for (int c = 0; c < C; ++c) {
        const short* bxs = &bxlds[c][0];

        // ---- per-channel zc quads from LDS (quad-uniform broadcast reads)
        f32x4 zcq[4];
#pragma unroll
        for (int nt = 0; nt < 4; ++nt)
            zcq[nt] = *(const f32x4*)&zclds[c][nt * 16 + 4 * quad];

        // ---- S1: x = mfma(ZWrows, feat, C=zc) + s2*w32 (rank-2 VALU fold)
        f32x4 x[2][4];
#pragma unroll
        for (int nt = 0; nt < 4; ++nt) {
            const int row = nt * 16 + l16;
            const int sw  = ((row >> 1) & 3) << 3;
            bf16x8 b0f = *(const bf16x8*)(bxs + row * 32 + ((quad * 8) ^ sw));
#pragma unroll
            for (int m = 0; m < 2; ++m) {
                f32x4 acc = __builtin_amdgcn_mfma_f32_16x16x32_bf16(b0f, a0[m], zcq[nt], 0, 0, 0);
#pragma unroll
                for (int r = 0; r < 4; ++r) acc[r] += s2m[m] * w32q[nt][r];
                x[m][nt] = acc;
            }
        }

        // ---- repack relu(x) -> B-frags (in-lane, zero shuffles)
        bf16x8 xf0[2], xf1[2];
#pragma unroll
        for (int m = 0; m < 2; ++m) repack_relu(x[m], xf0[m], xf1[m]);

        // ---- S2: h = relu(x) @ Wa0 + ba0
        f32x4 h[2][4];
#pragma unroll
        for (int nt = 0; nt < 4; ++nt) {
#pragma unroll
            for (int m = 0; m < 2; ++m) {
                f32x4 acc = __builtin_amdgcn_mfma_f32_16x16x32_bf16(wa0f[nt][0], xf0[m], ba0q[nt], 0, 0, 0);
                acc = __builtin_amdgcn_mfma_f32_16x16x32_bf16(wa0f[nt][1], xf1[m], acc, 0, 0, 0);
                h[m][nt] = acc;
            }
        }

        // ---- repack relu(h)
        bf16x8 hf0[2], hf1[2];
#pragma unroll
        for (int m = 0; m < 2; ++m) repack_relu(h[m], hf0[m], hf1[m]);

        // ---- S3: x + relu(h) @ Wb0 ; max-pool over c (bb0 folded post-loop)
#pragma unroll
        for (int nt = 0; nt < 4; ++nt) {
#pragma unroll
            for (int m = 0; m < 2; ++m) {
                f32x4 acc = __builtin_amdgcn_mfma_f32_16x16x32_bf16(wb0f[nt][0], hf0[m], x[m][nt], 0, 0, 0);
                acc = __builtin_amdgcn_mfma_f32_16x16x32_bf16(wb0f[nt][1], hf1[m], acc, 0, 0, 0);
#pragma unroll
                for (int r = 0; r < 4; ++r)
                    pooled[m][nt][r] = fmaxf(pooled[m][nt][r], acc[r]);
            }
        }
    }

    // ---- fold bb0 into pooled once (bb0 loaded HERE: not live in-loop)
    {
        f32x4 bb0q[4];
#pragma unroll
        for (int nt = 0; nt < 4; ++nt)
            bb0q[nt] = *(const f32x4*)(bb + nt * 16 + 4 * quad);
#pragma unroll
        for (int nt = 0; nt < 4; ++nt)
#pragma unroll
            for (int m = 0; m < 2; ++m)
#pragma unroll
                for (int r = 0; r < 4; ++r)
                    pooled[m][nt][r] += bb0q[nt][r];
    }

    // =============== residual blocks 1..4 (2 chains: m-tiles) ===============
#pragma unroll
    for (int i = 1; i < 5; ++i) {
        const short* wa = Wat + i * 4096;
        const short* wb = Wbt + i * 4096;
        float4 bai[4], bbi[4];
#pragma unroll
        for (int nt = 0; nt < 4; ++nt) {
            bai[nt] = *(const float4*)(ba + i * H + nt * 16 + 4 * quad);
            bbi[nt] = *(const float4*)(bb + i * H + nt * 16 + 4 * quad);
        }

        bf16x8 pf0[2], pf1[2];
#pragma unroll
        for (int m = 0; m < 2; ++m) repack_relu(pooled[m], pf0[m], pf1[m]);

        f32x4 h[2][4];
#pragma unroll
        for (int nt = 0; nt < 4; ++nt) {
            bf16x8 w0f = *(const bf16x8*)(wa + (nt * 16 + l16) * 64 + quad * 8);
            bf16x8 w1f = *(const bf16x8*)(wa + (nt * 16 + l16) * 64 + 32 + quad * 8);
#pragma unroll
            for (int m = 0; m < 2; ++m) {
                f32x4 acc = (f32x4){bai[nt].x, bai[nt].y, bai[nt].z, bai[nt].w};
                acc = __builtin_amdgcn_mfma_f32_16x16x32_bf16(w0f, pf0[m], acc, 0, 0, 0);
                acc = __builtin_amdgcn_mfma_f32_16x16x32_bf16(w1f, pf1[m], acc, 0, 0, 0);
                h[m][nt] = acc;
            }
        }

        bf16x8 hf0[2], hf1[2];
#pragma unroll
        for (int m = 0; m < 2; ++m) repack_relu(h[m], hf0[m], hf1[m]);

#pragma unroll
        for (int nt = 0; nt < 4; ++nt) {
            bf16x8 w0f = *(const bf16x8*)(wb + (nt * 16 + l16) * 64 + quad * 8);
            bf16x8 w1f = *(const bf16x8*)(wb + (nt * 16 + l16) * 64 + 32 + quad * 8);
#pragma unroll
            for (int m = 0; m < 2; ++m) {
                f32x4 acc = pooled[m][nt];
                acc[0] += bbi[nt].x; acc[1] += bbi[nt].y;
                acc[2] += bbi[nt].z; acc[3] += bbi[nt].w;
                acc = __builtin_amdgcn_mfma_f32_16x16x32_bf16(w0f, hf0[m], acc, 0, 0, 0);
                acc = __builtin_amdgcn_mfma_f32_16x16x32_bf16(w1f, hf1[m], acc, 0, 0, 0);
                pooled[m][nt] = acc;
            }
        }
    }

    // =============== head: per-lane dot + cross-quad reduce =================
    const float bo = bout[0];
    float4 wo4[4];
#pragma unroll
    for (int nt = 0; nt < 4; ++nt)
        wo4[nt] = *(const float4*)(Wout + nt * 16 + 4 * quad);
#pragma unroll
    for (int m = 0; m < 2; ++m) {
        float s = 0.f;
#pragma unroll
        for (int nt = 0; nt < 4; ++nt) {
            s += fmaxf(pooled[m][nt][0], 0.f) * wo4[nt].x
               + fmaxf(pooled[m][nt][1], 0.f) * wo4[nt].y
               + fmaxf(pooled[m][nt][2], 0.f) * wo4[nt].z
               + fmaxf(pooled[m][nt][3], 0.f) * wo4[nt].w;
        }
        s += __shfl_xor(s, 16);
        s += __shfl_xor(s, 32);
        if (lane < 16)
            out[(size_t)b * P + base + m * 16 + l16] = s + bo;
    }
}

extern "C" void kernel_launch(void* const* d_in, const int* in_sizes, int n_in,
                              void* d_out, int out_size, void* d_ws, size_t ws_size,
                              hipStream_t stream) {
    const float* z      = (const float*)d_in[0];
    const float* pos    = (const float*)d_in[1];
    const float* p      = (const float*)d_in[2];
    const float* W_feat = (const float*)d_in[3];
    const float* W_dir  = (const float*)d_in[4];
    const float* W0     = (const float*)d_in[5];
    const float* b0     = (const float*)d_in[6];
    const float* Wa     = (const float*)d_in[7];
    const float* ba     = (const float*)d_in[8];
    const float* Wb     = (const float*)d_in[9];
    const float* bb     = (const float*)d_in[10];
    const float* Wout   = (const float*)d_in[11];
    const float* bout   = (const float*)d_in[12];
    float* out = (float*)d_out;

    short* wsS = (short*)d_ws;
    short* Bxt = wsS;                     // B*C*64*32 shorts = 65536
    short* Wat = wsS + 32 * 2048;         // 5*4096
    short* Wbt = Wat + 5 * 4096;          // 5*4096
    float* zcA = (float*)(Wbt + 5 * 4096);// B*C*64 floats (16B-aligned)

    setup_kernel<<<112, 256, 0, stream>>>(z, W_dir, W0, b0, Wa, Wb,
                                          Bxt, Wat, Wbt, zcA);

    dim3 grid(P / 128, B);
    main_kernel<<<grid, 256, 0, stream>>>(p, pos, W_feat, W0, Bxt, Wat, Wbt,
                                          zcA, ba, bb, Wout, bout, out);
}

// Round 16
// 135.005 us; speedup vs baseline: 1.0691x; 1.0057x over previous
//
#include <hip/hip_runtime.h>
#include <math.h>

#define B 4
#define P 32768
#define C 8
#define F 32
#define D 64
#define H 64

typedef __attribute__((ext_vector_type(8))) short bf16x8;
typedef __attribute__((ext_vector_type(4))) float f32x4;

__device__ __forceinline__ short f2bf(float f) {
    union { float f; unsigned u; } v; v.f = f;
    unsigned r = (v.u + 0x7FFFu + ((v.u >> 16) & 1u)) >> 16;   // RNE
    return (short)r;
}

// packed f32x2 -> bf16x2 (RNE) in one VALU op
__device__ __forceinline__ unsigned cvt_pk_bf16(float lo, float hi) {
    unsigned r;
    asm("v_cvt_pk_bf16_f32 %0, %1, %2" : "=v"(r) : "v"(lo), "v"(hi));
    return r;
}

// async global->LDS, 16B per lane. LDS dest = wave-uniform base + lane*16;
// global src = per-lane address (guide §5).
__device__ __forceinline__ void gload_lds16(const void* g, void* s) {
    __builtin_amdgcn_global_load_lds(
        (const __attribute__((address_space(1))) unsigned*)g,
        (__attribute__((address_space(3))) unsigned*)s, 16, 0, 0);
}

// ---------------------------------------------------------------------------
// repack_relu (r7, verified): D-form accumulators -> B-frag pair IN-LANE.
// pi(32f+8q+j) = 16(2f+(j>>2)) + 4q + (j&3) permutes the k-axis so lane
// (q,l16)'s D-form values {n=16nt+4q+r} ARE its B-frags in register order.
// Weights absorb pi at setup. Cost: 16 fmax + 8 cvt_pk. No shuffles, no LDS.
// ---------------------------------------------------------------------------
__device__ __forceinline__ void repack_relu(const f32x4* v, bf16x8& f0, bf16x8& f1)
{
    union { unsigned u[4]; bf16x8 v8; } A, Bv;
    A.u[0]  = cvt_pk_bf16(fmaxf(v[0][0], 0.f), fmaxf(v[0][1], 0.f));
    A.u[1]  = cvt_pk_bf16(fmaxf(v[0][2], 0.f), fmaxf(v[0][3], 0.f));
    A.u[2]  = cvt_pk_bf16(fmaxf(v[1][0], 0.f), fmaxf(v[1][1], 0.f));
    A.u[3]  = cvt_pk_bf16(fmaxf(v[1][2], 0.f), fmaxf(v[1][3], 0.f));
    Bv.u[0] = cvt_pk_bf16(fmaxf(v[2][0], 0.f), fmaxf(v[2][1], 0.f));
    Bv.u[1] = cvt_pk_bf16(fmaxf(v[2][2], 0.f), fmaxf(v[2][3], 0.f));
    Bv.u[2] = cvt_pk_bf16(fmaxf(v[3][0], 0.f), fmaxf(v[3][1], 0.f));
    Bv.u[3] = cvt_pk_bf16(fmaxf(v[3][2], 0.f), fmaxf(v[3][3], 0.f));
    f0 = A.v8; f1 = Bv.v8;
}

// ---------------------------------------------------------------------------
// Merged setup kernel (r14 — verified). Bxt (B,C,64n,32k) ZW rows with
// swizzle short_idx ^= ((row>>1)&3)<<3 (conflict-free b128 service groups);
// zcA f32 sideband; pi-permuted Wa/Wb; direct-global W_dir/W0 reads.
// ---------------------------------------------------------------------------
__global__ __launch_bounds__(256)
void setup_kernel(const float* __restrict__ z,
                  const float* __restrict__ W_dir,
                  const float* __restrict__ W0,
                  const float* __restrict__ b0,
                  const float* __restrict__ Wa,
                  const float* __restrict__ Wb,
                  short* __restrict__ Bxt,
                  short* __restrict__ Wat,
                  short* __restrict__ Wbt,
                  float* __restrict__ zcA)
{
    if (blockIdx.x >= 32) {
        int idx = (blockIdx.x - 32) * 256 + threadIdx.x;  // < 5*64*64
        int i = idx >> 12, r = idx & 4095, ks = r >> 6, n = r & 63;
        int f = ks >> 5, q = (ks >> 3) & 3, j = ks & 7;
        int nin = 16 * (2 * f + (j >> 2)) + 4 * q + (j & 3);   // pi(kslot)
        int o   = (i << 12) + (n << 6) + ks;                   // [n_out][kslot]
        int src = (i << 12) + (nin << 6) + n;                  // W[i][nin][n]
        Wat[o] = f2bf(Wa[src]);
        Wbt[o] = f2bf(Wb[src]);
        return;
    }
    const int bc = blockIdx.x;
    const int t  = threadIdx.x & 63;     // output column n (natural row)
    const int g  = threadIdx.x >> 6;     // f-group 0..3
    const float* zb = z + (size_t)bc * F * D;

    __shared__ float zl[F][D];       // 8 KB
    __shared__ float zp[4][D];       // 1 KB
    __shared__ float zq[4][D];       // 1 KB

    for (int i = threadIdx.x; i < F * D; i += 256) zl[i >> 6][i & 63] = zb[i];
    __syncthreads();

    const int sw = ((t >> 1) & 3) << 3;               // r14 swizzle (shorts)
    short* brow = Bxt + ((size_t)bc * 64 + t) * 32;   // natural row = n, 32k

    float zi = 0.f;
    for (int f = g * 8; f < g * 8 + 8; ++f) {
        float z0 = 0, z1 = 0, z2 = 0, z3 = 0;
        float a0 = 0, a1 = 0, a2 = 0, a3 = 0;
#pragma unroll
        for (int d = 0; d < D; d += 4) {
            float4 z4 = *(const float4*)&zl[f][d];    // broadcast b128
            z0 += z4.x * W_dir[(d + 0) * D + t];
            z1 += z4.y * W_dir[(d + 1) * D + t];
            z2 += z4.z * W_dir[(d + 2) * D + t];
            z3 += z4.w * W_dir[(d + 3) * D + t];
            a0 += z4.x * W0[(1 + d + 0) * H + t];
            a1 += z4.y * W0[(1 + d + 1) * H + t];
            a2 += z4.z * W0[(1 + d + 2) * H + t];
            a3 += z4.w * W0[(1 + d + 3) * H + t];
        }
        zi += zl[f][t] * ((z0 + z1) + (z2 + z3));
        brow[f ^ sw] = f2bf((a0 + a1) + (a2 + a3));   // ZW row f, col t
    }
    zp[g][t] = zi;
    __syncthreads();
    if (g == 0) {
        float zall = zp[0][t] + zp[1][t] + zp[2][t] + zp[3][t];
        zp[0][t] = zall;                              // full z_inv[t]
    }
    __syncthreads();
    // zc partials: each g-group covers 16 e's
    {
        float zcp = 0.f;
        for (int e = g * 16; e < g * 16 + 16; ++e)
            zcp += zp[0][e] * W0[(65 + e) * H + t];
        zq[g][t] = zcp;
    }
    __syncthreads();
    if (g == 0) {
        float zc = b0[t] + zq[0][t] + zq[1][t] + zq[2][t] + zq[3][t];
        zcA[bc * 64 + t] = zc;                        // f32 sideband
    }
}

// ---------------------------------------------------------------------------
// Main (r14 — FINAL, verified 58.4 µs / 135.8 total):
// K=32 S1 (ZW rows only; zc as MFMA C-operand from LDS; s2*w32 rank-2 VALU
// fold), all-8-channel LDS staging with ONE barrier total (waves de-phase),
// (row>>1)&3 swizzle (conflict-free), swapped-operand MFMAs with pi-permuted
// k-axis -> in-lane repack (zero shuffles), bb0 folded post-loop.
// Session conclusion: latency-bound at the 4-waves/SIMD occupancy bucket
// (<=64-reg/8-wave bucket unreachable for this state footprint). Tested and
// exhausted: TLP(r1), reorder(r5), shuffle/in-lane transforms(r6/r7),
// no-LDS(r8/r9), barrier schedule(r10), setprio/bias-C(r11), setup
// variants(r12), K-shrink(r13/r14), packed-VALU(r15 -> VOP3P even-pair
// hazard, correctness fail). The remaining gap to the ~15 µs MFMA floor is
// the serial MFMA->repack->MFMA dependency chain of this algorithm shape.
// ---------------------------------------------------------------------------
__global__ __launch_bounds__(256, 2)
void main_kernel(const float* __restrict__ p,      // (B,P,3)
                 const float* __restrict__ pos,    // (B,3)
                 const float* __restrict__ W_feat, // (3,F)
                 const float* __restrict__ W0,     // (1+2D,H) — row 0 used
                 const short* __restrict__ Bxt,    // (B,C,64n,32k) bf16 (swz)
                 const short* __restrict__ Wat,    // (5,64n,64kslot) pi-perm
                 const short* __restrict__ Wbt,    // (5,64n,64kslot) pi-perm
                 const float* __restrict__ zcA,    // (B,C,64) f32
                 const float* __restrict__ ba,     // (5,H)
                 const float* __restrict__ bb,     // (5,H)
                 const float* __restrict__ Wout,   // (H,1)
                 const float* __restrict__ bout,   // (1,)
                 float* __restrict__ out)          // (B,P)
{
    const int wave = threadIdx.x >> 6;
    const int lane = threadIdx.x & 63;
    const int quad = lane >> 4;
    const int l16  = lane & 15;
    const int b    = blockIdx.y;
    const int base = blockIdx.x * 128 + wave * 32;

    __shared__ __attribute__((aligned(16))) short bxlds[8][2048]; // 32 KB
    __shared__ __attribute__((aligned(16))) float zclds[C][64];   // 2 KB

    const short* bxg = Bxt + (size_t)b * C * 2048;
    const float* zcb = zcA + (size_t)b * C * 64;

    // ---- stage ALL 8 channels + zc sideband (drained by single barrier)
#pragma unroll
    for (int c0 = 0; c0 < 8; ++c0) {
        const short* src = bxg + (size_t)c0 * 2048 + wave * 512 + lane * 8;
        gload_lds16(src, &bxlds[c0][wave * 512]);
    }
    if (wave < 2)
        gload_lds16(zcb + wave * 256 + lane * 4, &zclds[0][0] + wave * 256);

    // ---- point features -> B-frag (K=32) + per-point invariant s2
    bf16x8 a0[2];
    float s2m[2];
#pragma unroll
    for (int m = 0; m < 2; ++m) {
        const float* pp = p + ((size_t)b * P + base + m * 16 + l16) * 3;
        float px = pp[0] - pos[b * 3 + 0];
        float py = pp[1] - pos[b * 3 + 1];
        float pz = pp[2] - pos[b * 3 + 2];
        float nrm = sqrtf(px * px + py * py + pz * pz);
        if (nrm > 0.5f) { float s = 0.5f / nrm; px *= s; py *= s; pz *= s; }
        float av[8];
        float s2 = 0.f;
#pragma unroll
        for (int j = 0; j < 8; ++j) {
            int k = quad * 8 + j;
            av[j] = px * W_feat[k] + py * W_feat[F + k] + pz * W_feat[2 * F + k];
            s2 += av[j] * av[j];
        }
        s2 += __shfl_xor(s2, 16);
        s2 += __shfl_xor(s2, 32);
        s2m[m] = s2;
        union { bf16x8 v; unsigned u[4]; } ua;
#pragma unroll
        for (int j = 0; j < 4; ++j) ua.u[j] = cvt_pk_bf16(av[2 * j], av[2 * j + 1]);
        a0[m] = ua.v;
    }

    f32x4 pooled[2][4];
#pragma unroll
    for (int m = 0; m < 2; ++m)
#pragma unroll
        for (int nt = 0; nt < 4; ++nt)
            pooled[m][nt] = (f32x4){-1e30f, -1e30f, -1e30f, -1e30f};

    // ---- c-invariant vectors in D-form quads (n = 16nt + 4q + r)
    f32x4 ba0q[4], w32q[4];
#pragma unroll
    for (int nt = 0; nt < 4; ++nt) {
        ba0q[nt] = *(const f32x4*)(ba + nt * 16 + 4 * quad);
        w32q[nt] = *(const f32x4*)(W0 + nt * 16 + 4 * quad);   // W0 row 0
    }

    // ---- hoist layer-0 weight A-frags (c-invariant; 64 VGPRs)
    bf16x8 wa0f[4][2], wb0f[4][2];
#pragma unroll
    for (int nt = 0; nt < 4; ++nt) {
        wa0f[nt][0] = *(const bf16x8*)(Wat + (nt * 16 + l16) * 64 + quad * 8);
        wa0f[nt][1] = *(const bf16x8*)(Wat + (nt * 16 + l16) * 64 + 32 + quad * 8);
        wb0f[nt][0] = *(const bf16x8*)(Wbt + (nt * 16 + l16) * 64 + quad * 8);
        wb0f[nt][1] = *(const bf16x8*)(Wbt + (nt * 16 + l16) * 64 + 32 + quad * 8);
    }

    __syncthreads();   // the ONLY barrier: drains vmcnt, publishes LDS

    // =============== c-loop: ZERO barriers, waves de-phase ==================
#pragma unroll 1
    for (int c = 0; c < C; ++c) {
        const short* bxs = &bxlds[c][0];

        // ---- per-channel zc quads from LDS (quad-uniform broadcast reads)
        f32x4 zcq[4];
#pragma unroll
        for (int nt = 0; nt < 4; ++nt)
            zcq[nt] = *(const f32x4*)&zclds[c][nt * 16 + 4 * quad];

        // ---- S1: x = mfma(ZWrows, feat, C=zc) + s2*w32 (rank-2 VALU fold)
        f32x4 x[2][4];
#pragma unroll
        for (int nt = 0; nt < 4; ++nt) {
            const int row = nt * 16 + l16;
            const int sw  = ((row >> 1) & 3) << 3;
            bf16x8 b0f = *(const bf16x8*)(bxs + row * 32 + ((quad * 8) ^ sw));
#pragma unroll
            for (int m = 0; m < 2; ++m) {
                f32x4 acc = __builtin_amdgcn_mfma_f32_16x16x32_bf16(b0f, a0[m], zcq[nt], 0, 0, 0);
#pragma unroll
                for (int r = 0; r < 4; ++r) acc[r] += s2m[m] * w32q[nt][r];
                x[m][nt] = acc;
            }
        }

        // ---- repack relu(x) -> B-frags (in-lane, zero shuffles)
        bf16x8 xf0[2], xf1[2];
#pragma unroll
        for (int m = 0; m < 2; ++m) repack_relu(x[m], xf0[m], xf1[m]);

        // ---- S2: h = relu(x) @ Wa0 + ba0
        f32x4 h[2][4];
#pragma unroll
        for (int nt = 0; nt < 4; ++nt) {
#pragma unroll
            for (int m = 0; m < 2; ++m) {
                f32x4 acc = __builtin_amdgcn_mfma_f32_16x16x32_bf16(wa0f[nt][0], xf0[m], ba0q[nt], 0, 0, 0);
                acc = __builtin_amdgcn_mfma_f32_16x16x32_bf16(wa0f[nt][1], xf1[m], acc, 0, 0, 0);
                h[m][nt] = acc;
            }
        }

        // ---- repack relu(h)
        bf16x8 hf0[2], hf1[2];
#pragma unroll
        for (int m = 0; m < 2; ++m) repack_relu(h[m], hf0[m], hf1[m]);

        // ---- S3: x + relu(h) @ Wb0 ; max-pool over c (bb0 folded post-loop)
#pragma unroll
        for (int nt = 0; nt < 4; ++nt) {
#pragma unroll
            for (int m = 0; m < 2; ++m) {
                f32x4 acc = __builtin_amdgcn_mfma_f32_16x16x32_bf16(wb0f[nt][0], hf0[m], x[m][nt], 0, 0, 0);
                acc = __builtin_amdgcn_mfma_f32_16x16x32_bf16(wb0f[nt][1], hf1[m], acc, 0, 0, 0);
#pragma unroll
                for (int r = 0; r < 4; ++r)
                    pooled[m][nt][r] = fmaxf(pooled[m][nt][r], acc[r]);
            }
        }
    }

    // ---- fold bb0 into pooled once (bb0 loaded HERE: not live in-loop)
    {
        f32x4 bb0q[4];
#pragma unroll
        for (int nt = 0; nt < 4; ++nt)
            bb0q[nt] = *(const f32x4*)(bb + nt * 16 + 4 * quad);
#pragma unroll
        for (int nt = 0; nt < 4; ++nt)
#pragma unroll
            for (int m = 0; m < 2; ++m)
#pragma unroll
                for (int r = 0; r < 4; ++r)
                    pooled[m][nt][r] += bb0q[nt][r];
    }

    // =============== residual blocks 1..4 (2 chains: m-tiles) ===============
#pragma unroll
    for (int i = 1; i < 5; ++i) {
        const short* wa = Wat + i * 4096;
        const short* wb = Wbt + i * 4096;
        float4 bai[4], bbi[4];
#pragma unroll
        for (int nt = 0; nt < 4; ++nt) {
            bai[nt] = *(const float4*)(ba + i * H + nt * 16 + 4 * quad);
            bbi[nt] = *(const float4*)(bb + i * H + nt * 16 + 4 * quad);
        }

        bf16x8 pf0[2], pf1[2];
#pragma unroll
        for (int m = 0; m < 2; ++m) repack_relu(pooled[m], pf0[m], pf1[m]);

        f32x4 h[2][4];
#pragma unroll
        for (int nt = 0; nt < 4; ++nt) {
            bf16x8 w0f = *(const bf16x8*)(wa + (nt * 16 + l16) * 64 + quad * 8);
            bf16x8 w1f = *(const bf16x8*)(wa + (nt * 16 + l16) * 64 + 32 + quad * 8);
#pragma unroll
            for (int m = 0; m < 2; ++m) {
                f32x4 acc = (f32x4){bai[nt].x, bai[nt].y, bai[nt].z, bai[nt].w};
                acc = __builtin_amdgcn_mfma_f32_16x16x32_bf16(w0f, pf0[m], acc, 0, 0, 0);
                acc = __builtin_amdgcn_mfma_f32_16x16x32_bf16(w1f, pf1[m], acc, 0, 0, 0);
                h[m][nt] = acc;
            }
        }

        bf16x8 hf0[2], hf1[2];
#pragma unroll
        for (int m = 0; m < 2; ++m) repack_relu(h[m], hf0[m], hf1[m]);

#pragma unroll
        for (int nt = 0; nt < 4; ++nt) {
            bf16x8 w0f = *(const bf16x8*)(wb + (nt * 16 + l16) * 64 + quad * 8);
            bf16x8 w1f = *(const bf16x8*)(wb + (nt * 16 + l16) * 64 + 32 + quad * 8);
#pragma unroll
            for (int m = 0; m < 2; ++m) {
                f32x4 acc = pooled[m][nt];
                acc[0] += bbi[nt].x; acc[1] += bbi[nt].y;
                acc[2] += bbi[nt].z; acc[3] += bbi[nt].w;
                acc = __builtin_amdgcn_mfma_f32_16x16x32_bf16(w0f, hf0[m], acc, 0, 0, 0);
                acc = __builtin_amdgcn_mfma_f32_16x16x32_bf16(w1f, hf1[m], acc, 0, 0, 0);
                pooled[m][nt] = acc;
            }
        }
    }

    // =============== head: per-lane dot + cross-quad reduce =================
    const float bo = bout[0];
    float4 wo4[4];
#pragma unroll
    for (int nt = 0; nt < 4; ++nt)
        wo4[nt] = *(const float4*)(Wout + nt * 16 + 4 * quad);
#pragma unroll
    for (int m = 0; m < 2; ++m) {
        float s = 0.f;
#pragma unroll
        for (int nt = 0; nt < 4; ++nt) {
            s += fmaxf(pooled[m][nt][0], 0.f) * wo4[nt].x
               + fmaxf(pooled[m][nt][1], 0.f) * wo4[nt].y
               + fmaxf(pooled[m][nt][2], 0.f) * wo4[nt].z
               + fmaxf(pooled[m][nt][3], 0.f) * wo4[nt].w;
        }
        s += __shfl_xor(s, 16);
        s += __shfl_xor(s, 32);
        if (lane < 16)
            out[(size_t)b * P + base + m * 16 + l16] = s + bo;
    }
}

extern "C" void kernel_launch(void* const* d_in, const int* in_sizes, int n_in,
                              void* d_out, int out_size, void* d_ws, size_t ws_size,
                              hipStream_t stream) {
    const float* z      = (const float*)d_in[0];
    const float* pos    = (const float*)d_in[1];
    const float* p      = (const float*)d_in[2];
    const float* W_feat = (const float*)d_in[3];
    const float* W_dir  = (const float*)d_in[4];
    const float* W0     = (const float*)d_in[5];
    const float* b0     = (const float*)d_in[6];
    const float* Wa     = (const float*)d_in[7];
    const float* ba     = (const float*)d_in[8];
    const float* Wb     = (const float*)d_in[9];
    const float* bb     = (const float*)d_in[10];
    const float* Wout   = (const float*)d_in[11];
    const float* bout   = (const float*)d_in[12];
    float* out = (float*)d_out;

    short* wsS = (short*)d_ws;
    short* Bxt = wsS;                     // B*C*64*32 shorts = 65536
    short* Wat = wsS + 32 * 2048;         // 5*4096
    short* Wbt = Wat + 5 * 4096;          // 5*4096
    float* zcA = (float*)(Wbt + 5 * 4096);// B*C*64 floats (16B-aligned)

    setup_kernel<<<112, 256, 0, stream>>>(z, W_dir, W0, b0, Wa, Wb,
                                          Bxt, Wat, Wbt, zcA);

    dim3 grid(P / 128, B);
    main_kernel<<<grid, 256, 0, stream>>>(p, pos, W_feat, W0, Bxt, Wat, Wbt,
                                          zcA, ba, bb, Wout, bout, out);
}